// Round 1
// baseline (409.575 us; speedup 1.0000x reference)
//
#include <hip/hip_runtime.h>

constexpr int B = 4, S = 2048, U = 1024, H = 16, DH = 64;
constexpr int MTOT = B * S;

using bf16   = __bf16;
using f32x4  = __attribute__((ext_vector_type(4))) float;
using bf16x8 = __attribute__((ext_vector_type(8))) bf16;
using bf16x4 = __attribute__((ext_vector_type(4))) bf16;

// ---------- weight transpose + convert: Wt[n][k] = (bf16) W[k][n] ----------
__global__ void transpose_w_kernel(const float* __restrict__ w0, const float* __restrict__ w1,
                                   const float* __restrict__ w2, const float* __restrict__ w3,
                                   bf16* __restrict__ t0, bf16* __restrict__ t1,
                                   bf16* __restrict__ t2, bf16* __restrict__ t3) {
  const float* W = blockIdx.z == 0 ? w0 : blockIdx.z == 1 ? w1 : blockIdx.z == 2 ? w2 : w3;
  bf16* Wt       = blockIdx.z == 0 ? t0 : blockIdx.z == 1 ? t1 : blockIdx.z == 2 ? t2 : t3;
  __shared__ float tile[32][33];
  const int k0 = blockIdx.x * 32, n0 = blockIdx.y * 32;
  const int tx = threadIdx.x, ty = threadIdx.y;
  for (int i = ty; i < 32; i += 8) tile[i][tx] = W[(size_t)(k0 + i) * U + n0 + tx];
  __syncthreads();
  for (int i = ty; i < 32; i += 8) Wt[(size_t)(n0 + i) * U + k0 + tx] = (bf16)tile[tx][i];
}

// ---------- 4 fused GEMMs: out = relu(X @ W + b), bf16 out ----------
// A = X fp32 [8192][1024] (converted to bf16 during staging), B^T = Wt bf16 [n][k]
__global__ __launch_bounds__(256) void gemm4_kernel(
    const float* __restrict__ xq, const float* __restrict__ xk, const float* __restrict__ xv,
    const bf16* __restrict__ wqt, const bf16* __restrict__ wkt,
    const bf16* __restrict__ wvt, const bf16* __restrict__ wrt,
    const float* __restrict__ bq, const float* __restrict__ bk,
    const float* __restrict__ bv, const float* __restrict__ br,
    bf16* __restrict__ oq, bf16* __restrict__ ok,
    bf16* __restrict__ ov, bf16* __restrict__ orr) {
  const int z = blockIdx.z;
  const float* X    = z == 0 ? xq : z == 1 ? xk : xv;   // z==2,3 both read `values`
  const bf16*  Wt   = z == 0 ? wqt : z == 1 ? wkt : z == 2 ? wvt : wrt;
  const float* bias = z == 0 ? bq : z == 1 ? bk : z == 2 ? bv : br;
  bf16* out         = z == 0 ? oq : z == 1 ? ok : z == 2 ? ov : orr;

  const int bn = blockIdx.x * 128;
  const int bm = blockIdx.y * 128;
  const int t = threadIdx.x;
  const int lane = t & 63, wid = t >> 6;
  const int wr = wid >> 1, wc = wid & 1;
  const int lm = lane & 15, lk = (lane >> 4) * 8;

  __shared__ bf16 As[128][40];   // +8 pad -> ~2-way banks on b128 reads
  __shared__ bf16 Bs[128][40];

  f32x4 acc[4][4];
#pragma unroll
  for (int i = 0; i < 4; ++i)
#pragma unroll
    for (int j = 0; j < 4; ++j) acc[i][j] = f32x4{0.f, 0.f, 0.f, 0.f};

  for (int k0 = 0; k0 < U; k0 += 32) {
    __syncthreads();
    // stage A: 128x32 fp32 -> bf16 (8 lanes/row, 128B contiguous per row)
#pragma unroll
    for (int j = 0; j < 4; ++j) {
      const int c = t + 256 * j;
      const int row = c >> 3, col = (c & 7) * 4;
      const float4 v = *reinterpret_cast<const float4*>(&X[(size_t)(bm + row) * U + k0 + col]);
      bf16x4 o;
      o[0] = (bf16)v.x; o[1] = (bf16)v.y; o[2] = (bf16)v.z; o[3] = (bf16)v.w;
      *reinterpret_cast<bf16x4*>(&As[row][col]) = o;
    }
    // stage B: Wt rows bn..bn+127, 32 bf16 each
#pragma unroll
    for (int j = 0; j < 2; ++j) {
      const int c = t + 256 * j;
      const int row = c >> 2, col = (c & 3) * 8;
      *reinterpret_cast<int4*>(&Bs[row][col]) =
          *reinterpret_cast<const int4*>(&Wt[(size_t)(bn + row) * U + k0 + col]);
    }
    __syncthreads();

    bf16x8 a[4], bfr[4];
#pragma unroll
    for (int mi = 0; mi < 4; ++mi)
      a[mi] = *reinterpret_cast<const bf16x8*>(&As[wr * 64 + mi * 16 + lm][lk]);
#pragma unroll
    for (int ni = 0; ni < 4; ++ni)
      bfr[ni] = *reinterpret_cast<const bf16x8*>(&Bs[wc * 64 + ni * 16 + lm][lk]);
#pragma unroll
    for (int mi = 0; mi < 4; ++mi)
#pragma unroll
      for (int ni = 0; ni < 4; ++ni)
        acc[mi][ni] = __builtin_amdgcn_mfma_f32_16x16x32_bf16(a[mi], bfr[ni], acc[mi][ni], 0, 0, 0);
  }

  // epilogue: bias + relu, bf16 store. C layout: col=lane&15, row=(lane>>4)*4+reg
  const int mb = bm + wr * 64 + (lane >> 4) * 4;
  const int nb = bn + wc * 64 + lm;
#pragma unroll
  for (int ni = 0; ni < 4; ++ni) {
    const float bv_ = bias[nb + ni * 16];
#pragma unroll
    for (int mi = 0; mi < 4; ++mi)
#pragma unroll
      for (int r = 0; r < 4; ++r) {
        float vv = acc[mi][ni][r] + bv_;
        vv = fmaxf(vv, 0.f);
        out[(size_t)(mb + mi * 16 + r) * U + nb + ni * 16] = (bf16)vv;
      }
  }
}

// ---------- V transpose per head: Vt[(b*H+h)*DH + d][s] = V[b*S + s][h*DH + d] ----------
__global__ void transpose_v_kernel(const bf16* __restrict__ V, bf16* __restrict__ Vt) {
  __shared__ bf16 tile[32][33];
  const int bh = blockIdx.z;       // b*H + h
  const int b = bh >> 4, h = bh & 15;
  const int s0 = blockIdx.x * 32, d0 = blockIdx.y * 32;
  const int tx = threadIdx.x, ty = threadIdx.y;
  for (int i = ty; i < 32; i += 8)
    tile[i][tx] = V[((size_t)b * S + s0 + i) * U + h * DH + d0 + tx];
  __syncthreads();
  for (int i = ty; i < 32; i += 8)
    Vt[((size_t)bh * DH + d0 + i) * S + s0 + tx] = tile[tx][i];
}

// ---------- flash attention: per (b,h), Q-tile=64 (4 waves x 16 rows), K-tile=64 ----------
__global__ __launch_bounds__(256) void attn_kernel(
    const bf16* __restrict__ Q, const bf16* __restrict__ K,
    const bf16* __restrict__ Vt, bf16* __restrict__ att) {
  const int bh = blockIdx.y;
  const int b = bh >> 4, h = bh & 15;
  const int q0 = blockIdx.x * 64;
  const int t = threadIdx.x;
  const int lane = t & 63, wid = t >> 6;
  const int lm = lane & 15, lkof = (lane >> 4) * 8;

  __shared__ bf16 Ks[64][72];        // [key][d]
  __shared__ bf16 Vs[64][72];        // [d][key]  (from Vt)
  __shared__ bf16 Ps[4][16][72];     // wave-private P tiles [qrow][key]

  // hoist Q fragments (A operand, K-dim = 64 -> 2 ksteps)
  const bf16* qptr = Q + ((size_t)b * S + q0 + wid * 16 + lm) * U + h * DH;
  bf16x8 aq[2];
  aq[0] = *reinterpret_cast<const bf16x8*>(qptr + lkof);
  aq[1] = *reinterpret_cast<const bf16x8*>(qptr + 32 + lkof);

  float m_st[4], l_st[4];
  f32x4 acc_o[4];
#pragma unroll
  for (int r = 0; r < 4; ++r) { m_st[r] = -1e30f; l_st[r] = 0.f; }
#pragma unroll
  for (int d = 0; d < 4; ++d) acc_o[d] = f32x4{0.f, 0.f, 0.f, 0.f};

  for (int kt0 = 0; kt0 < S; kt0 += 64) {
    __syncthreads();
#pragma unroll
    for (int j = 0; j < 2; ++j) {
      const int c = t + 256 * j;
      const int row = c >> 3, col = (c & 7) * 8;
      *reinterpret_cast<int4*>(&Ks[row][col]) =
          *reinterpret_cast<const int4*>(&K[((size_t)b * S + kt0 + row) * U + h * DH + col]);
      *reinterpret_cast<int4*>(&Vs[row][col]) =
          *reinterpret_cast<const int4*>(&Vt[((size_t)bh * DH + row) * S + kt0 + col]);
    }
    __syncthreads();

    // S = Q K^T  (scores), acc layout: row=q (lane>>4)*4+r, col=key ni*16+lm
    f32x4 s_acc[4];
#pragma unroll
    for (int ni = 0; ni < 4; ++ni) s_acc[ni] = f32x4{0.f, 0.f, 0.f, 0.f};
#pragma unroll
    for (int ks = 0; ks < 2; ++ks)
#pragma unroll
      for (int ni = 0; ni < 4; ++ni) {
        bf16x8 bk = *reinterpret_cast<const bf16x8*>(&Ks[ni * 16 + lm][ks * 32 + lkof]);
        s_acc[ni] = __builtin_amdgcn_mfma_f32_16x16x32_bf16(aq[ks], bk, s_acc[ni], 0, 0, 0);
      }

    // online softmax over this 64-key tile
    float sc[4][4], pmax[4];
#pragma unroll
    for (int r = 0; r < 4; ++r) pmax[r] = -1e30f;
#pragma unroll
    for (int ni = 0; ni < 4; ++ni)
#pragma unroll
      for (int r = 0; r < 4; ++r) {
        sc[ni][r] = s_acc[ni][r] * 0.125f;   // 1/sqrt(64)
        pmax[r] = fmaxf(pmax[r], sc[ni][r]);
      }
#pragma unroll
    for (int r = 0; r < 4; ++r)
#pragma unroll
      for (int msk = 1; msk < 16; msk <<= 1)
        pmax[r] = fmaxf(pmax[r], __shfl_xor(pmax[r], msk));

    float fac[4], psum[4];
#pragma unroll
    for (int r = 0; r < 4; ++r) {
      const float mn = fmaxf(m_st[r], pmax[r]);
      fac[r] = __expf(m_st[r] - mn);
      m_st[r] = mn;
      psum[r] = 0.f;
    }
    const int prow = (lane >> 4) * 4;
#pragma unroll
    for (int ni = 0; ni < 4; ++ni)
#pragma unroll
      for (int r = 0; r < 4; ++r) {
        const float p = __expf(sc[ni][r] - m_st[r]);
        psum[r] += p;
        Ps[wid][prow + r][ni * 16 + lm] = (bf16)p;
      }
#pragma unroll
    for (int r = 0; r < 4; ++r) {
#pragma unroll
      for (int msk = 1; msk < 16; msk <<= 1) psum[r] += __shfl_xor(psum[r], msk);
      l_st[r] = l_st[r] * fac[r] + psum[r];
    }
#pragma unroll
    for (int d = 0; d < 4; ++d)
#pragma unroll
      for (int r = 0; r < 4; ++r) acc_o[d][r] *= fac[r];

    // O += P V   (A = Ps wave-private; compiler preserves ds-write->ds-read order)
#pragma unroll
    for (int ks = 0; ks < 2; ++ks) {
      bf16x8 ap = *reinterpret_cast<const bf16x8*>(&Ps[wid][lm][ks * 32 + lkof]);
#pragma unroll
      for (int d = 0; d < 4; ++d) {
        bf16x8 bv = *reinterpret_cast<const bf16x8*>(&Vs[d * 16 + lm][ks * 32 + lkof]);
        acc_o[d] = __builtin_amdgcn_mfma_f32_16x16x32_bf16(ap, bv, acc_o[d], 0, 0, 0);
      }
    }
  }

  // normalize + store bf16
#pragma unroll
  for (int d = 0; d < 4; ++d)
#pragma unroll
    for (int r = 0; r < 4; ++r) {
      const float v = acc_o[d][r] / l_st[r];
      att[((size_t)b * S + q0 + wid * 16 + (lane >> 4) * 4 + r) * U + h * DH + d * 16 + lm] = (bf16)v;
    }
}

// ---------- epilogue: x = relu(att + vres); LayerNorm(x)*gamma + beta ----------
__global__ __launch_bounds__(256) void ln_kernel(
    const bf16* __restrict__ att, const bf16* __restrict__ vres,
    const float* __restrict__ gamma, const float* __restrict__ beta,
    float* __restrict__ out) {
  const int row = blockIdx.x;
  const int t = threadIdx.x;
  const bf16* ar = att + (size_t)row * U;
  const bf16* vr = vres + (size_t)row * U;
  const bf16x4 av = *reinterpret_cast<const bf16x4*>(ar + t * 4);
  const bf16x4 vv = *reinterpret_cast<const bf16x4*>(vr + t * 4);
  float x[4];
  float sum = 0.f, sq = 0.f;
#pragma unroll
  for (int i = 0; i < 4; ++i) {
    x[i] = fmaxf((float)av[i] + (float)vv[i], 0.f);
    sum += x[i];
    sq += x[i] * x[i];
  }
#pragma unroll
  for (int m = 1; m < 64; m <<= 1) {
    sum += __shfl_xor(sum, m);
    sq  += __shfl_xor(sq, m);
  }
  __shared__ float s1[4], s2[4];
  if ((t & 63) == 0) { s1[t >> 6] = sum; s2[t >> 6] = sq; }
  __syncthreads();
  sum = s1[0] + s1[1] + s1[2] + s1[3];
  sq  = s2[0] + s2[1] + s2[2] + s2[3];
  const float mean = sum * (1.f / U);
  float var = sq * (1.f / U) - mean * mean;
  var = fmaxf(var, 0.f);
  const float inv = rsqrtf(var + 1e-8f);
#pragma unroll
  for (int i = 0; i < 4; ++i) {
    const int c = t * 4 + i;
    out[(size_t)row * U + c] = gamma[c] * ((x[i] - mean) * inv) + beta[c];
  }
}

extern "C" void kernel_launch(void* const* d_in, const int* in_sizes, int n_in,
                              void* d_out, int out_size, void* d_ws, size_t ws_size,
                              hipStream_t stream) {
  const float* queries = (const float*)d_in[0];
  const float* keys    = (const float*)d_in[1];
  const float* values  = (const float*)d_in[2];
  const float* Wq = (const float*)d_in[3];
  const float* bq = (const float*)d_in[4];
  const float* Wk = (const float*)d_in[5];
  const float* bk = (const float*)d_in[6];
  const float* Wv = (const float*)d_in[7];
  const float* bv = (const float*)d_in[8];
  const float* Wr = (const float*)d_in[9];
  const float* br = (const float*)d_in[10];
  const float* gamma = (const float*)d_in[11];
  const float* beta  = (const float*)d_in[12];
  float* out = (float*)d_out;

  char* ws = (char*)d_ws;
  const size_t szW = (size_t)U * U * sizeof(bf16);      // 2 MiB
  const size_t szM = (size_t)MTOT * U * sizeof(bf16);   // 16 MiB
  bf16* wqt = (bf16*)(ws + 0 * szW);
  bf16* wkt = (bf16*)(ws + 1 * szW);
  bf16* wvt = (bf16*)(ws + 2 * szW);
  bf16* wrt = (bf16*)(ws + 3 * szW);
  bf16* Qb  = (bf16*)(ws + 4 * szW + 0 * szM);
  bf16* Kb  = (bf16*)(ws + 4 * szW + 1 * szM);
  bf16* Vb  = (bf16*)(ws + 4 * szW + 2 * szM);
  bf16* Rb  = (bf16*)(ws + 4 * szW + 3 * szM);
  bf16* Vtb = (bf16*)(ws + 4 * szW + 4 * szM);
  bf16* attb= (bf16*)(ws + 4 * szW + 5 * szM);

  transpose_w_kernel<<<dim3(U / 32, U / 32, 4), dim3(32, 8), 0, stream>>>(
      Wq, Wk, Wv, Wr, wqt, wkt, wvt, wrt);
  gemm4_kernel<<<dim3(U / 128, MTOT / 128, 4), dim3(256), 0, stream>>>(
      queries, keys, values, wqt, wkt, wvt, wrt, bq, bk, bv, br, Qb, Kb, Vb, Rb);
  transpose_v_kernel<<<dim3(S / 32, DH / 32, B * H), dim3(32, 8), 0, stream>>>(Vb, Vtb);
  attn_kernel<<<dim3(S / 64, B * H), dim3(256), 0, stream>>>(Qb, Kb, Vtb, attb);
  ln_kernel<<<dim3(MTOT), dim3(256), 0, stream>>>(attb, Rb, gamma, beta, out);
}

// Round 2
// 403.401 us; speedup vs baseline: 1.0153x; 1.0153x over previous
//
#include <hip/hip_runtime.h>

constexpr int B = 4, S = 2048, U = 1024, H = 16, DH = 64;
constexpr int MTOT = B * S;

using bf16   = __bf16;
using f32x4  = __attribute__((ext_vector_type(4))) float;
using bf16x8 = __attribute__((ext_vector_type(8))) bf16;
using bf16x4 = __attribute__((ext_vector_type(4))) bf16;

__device__ __forceinline__ void gload16(const bf16* g, bf16* l) {
  __builtin_amdgcn_global_load_lds(
      (const __attribute__((address_space(1))) unsigned int*)g,
      (__attribute__((address_space(3))) unsigned int*)l, 16, 0, 0);
}

__device__ __forceinline__ float fexp2(float x) {
#if __has_builtin(__builtin_amdgcn_exp2f)
  return __builtin_amdgcn_exp2f(x);
#else
  return __expf(x * 0.6931471805599453f);
#endif
}

// ---------- weight transpose + convert: Wt[n][k] = (bf16) W[k][n] ----------
__global__ void transpose_w_kernel(const float* __restrict__ w0, const float* __restrict__ w1,
                                   const float* __restrict__ w2, const float* __restrict__ w3,
                                   bf16* __restrict__ t0, bf16* __restrict__ t1,
                                   bf16* __restrict__ t2, bf16* __restrict__ t3) {
  const float* W = blockIdx.z == 0 ? w0 : blockIdx.z == 1 ? w1 : blockIdx.z == 2 ? w2 : w3;
  bf16* Wt       = blockIdx.z == 0 ? t0 : blockIdx.z == 1 ? t1 : blockIdx.z == 2 ? t2 : t3;
  __shared__ float tile[32][33];
  const int k0 = blockIdx.x * 32, n0 = blockIdx.y * 32;
  const int tx = threadIdx.x, ty = threadIdx.y;
  for (int i = ty; i < 32; i += 8) tile[i][tx] = W[(size_t)(k0 + i) * U + n0 + tx];
  __syncthreads();
  for (int i = ty; i < 32; i += 8) Wt[(size_t)(n0 + i) * U + k0 + tx] = (bf16)tile[tx][i];
}

// ---------- fp32 -> bf16 convert ----------
__global__ __launch_bounds__(256) void xcvt_kernel(const float* __restrict__ x, bf16* __restrict__ o) {
  const size_t i = ((size_t)blockIdx.x * 256 + threadIdx.x) * 8;
  const float4 v0 = *reinterpret_cast<const float4*>(x + i);
  const float4 v1 = *reinterpret_cast<const float4*>(x + i + 4);
  bf16x8 r;
  r[0] = (bf16)v0.x; r[1] = (bf16)v0.y; r[2] = (bf16)v0.z; r[3] = (bf16)v0.w;
  r[4] = (bf16)v1.x; r[5] = (bf16)v1.y; r[6] = (bf16)v1.z; r[7] = (bf16)v1.w;
  *reinterpret_cast<bf16x8*>(o + i) = r;
}

// ---------- GEMM: out = relu(A @ Wt^T + b), A bf16 [M][U], Wt bf16 [n][k] ----------
__global__ __launch_bounds__(256) void gemm_kernel(
    const bf16* __restrict__ A, const bf16* __restrict__ Wt,
    const float* __restrict__ bias, bf16* __restrict__ out) {
  const int bn = blockIdx.x * 128, bm = blockIdx.y * 128;
  const int t = threadIdx.x, lane = t & 63, wid = t >> 6;
  const int wr = wid >> 1, wc = wid & 1;
  const int lm = lane & 15, hi = lane >> 4;

  __shared__ __align__(16) bf16 As[128][32];
  __shared__ __align__(16) bf16 Bs[128][32];

  f32x4 acc[4][4];
#pragma unroll
  for (int i = 0; i < 4; ++i)
#pragma unroll
    for (int j = 0; j < 4; ++j) acc[i][j] = f32x4{0.f, 0.f, 0.f, 0.f};

  const int srow = wid * 32 + (lane >> 2);
  const int scol = (lane & 3) * 8;
  const bf16* ga = A  + (size_t)(bm + srow) * U + scol;
  const bf16* gb = Wt + (size_t)(bn + srow) * U + scol;
  bf16* lA0 = &As[wid * 32][0];
  bf16* lA1 = &As[wid * 32 + 16][0];
  bf16* lB0 = &Bs[wid * 32][0];
  bf16* lB1 = &Bs[wid * 32 + 16][0];

  for (int k0 = 0; k0 < U; k0 += 32) {
    __syncthreads();
    gload16(ga + k0, lA0);
    gload16(ga + (size_t)16 * U + k0, lA1);
    gload16(gb + k0, lB0);
    gload16(gb + (size_t)16 * U + k0, lB1);
    __syncthreads();

    bf16x8 a[4], bb[4];
#pragma unroll
    for (int mi = 0; mi < 4; ++mi)
      a[mi] = *reinterpret_cast<const bf16x8*>(&As[wr * 64 + mi * 16 + lm][hi * 8]);
#pragma unroll
    for (int ni = 0; ni < 4; ++ni)
      bb[ni] = *reinterpret_cast<const bf16x8*>(&Bs[wc * 64 + ni * 16 + lm][hi * 8]);
#pragma unroll
    for (int mi = 0; mi < 4; ++mi)
#pragma unroll
      for (int ni = 0; ni < 4; ++ni)
        acc[mi][ni] = __builtin_amdgcn_mfma_f32_16x16x32_bf16(a[mi], bb[ni], acc[mi][ni], 0, 0, 0);
  }

  const int mb = bm + wr * 64 + hi * 4;
  const int nb = bn + wc * 64 + lm;
#pragma unroll
  for (int ni = 0; ni < 4; ++ni) {
    const float bv_ = bias[nb + ni * 16];
#pragma unroll
    for (int mi = 0; mi < 4; ++mi)
#pragma unroll
      for (int r = 0; r < 4; ++r) {
        float vv = acc[mi][ni][r] + bv_;
        vv = fmaxf(vv, 0.f);
        out[(size_t)(mb + mi * 16 + r) * U + nb + ni * 16] = (bf16)vv;
      }
  }
}

// ---------- V transpose per head: Vt[(b*H+h)*DH + d][s] = V[b*S + s][h*DH + d] ----------
__global__ void transpose_v_kernel(const bf16* __restrict__ V, bf16* __restrict__ Vt) {
  __shared__ bf16 tile[32][33];
  const int bh = blockIdx.z;
  const int b = bh >> 4, h = bh & 15;
  const int s0 = blockIdx.x * 32, d0 = blockIdx.y * 32;
  const int tx = threadIdx.x, ty = threadIdx.y;
  for (int i = ty; i < 32; i += 8)
    tile[i][tx] = V[((size_t)b * S + s0 + i) * U + h * DH + d0 + tx];
  __syncthreads();
  for (int i = ty; i < 32; i += 8)
    Vt[((size_t)bh * DH + d0 + i) * S + s0 + tx] = tile[tx][i];
}

// ---------- flash attention: 128 q-rows/block, 4 waves x 32 rows, no barriers ----------
__global__ __launch_bounds__(256) void attn_kernel(
    const bf16* __restrict__ Q, const bf16* __restrict__ K,
    const bf16* __restrict__ Vt, bf16* __restrict__ att) {
  const int bid = blockIdx.x;
  const int swz = (bid & 7) * 128 + (bid >> 3);     // XCD-chunk: 8 bh per XCD
  const int bh = swz >> 4, qx = swz & 15;
  const int b = bh >> 4, h = bh & 15;
  const int q0 = qx * 128;
  const int t = threadIdx.x, lane = t & 63, w = t >> 6;
  const int lm = lane & 15, hi = lane >> 4;

  __shared__ __align__(16) char Ps[4][2][16 * 128];  // wave-private P, XOR-swizzled rows

  const float qscale = 0.18033688011111606f;  // log2(e) / sqrt(DH)

  // hoist + pre-scale Q fragments (A-operand, 2 qm sub-tiles x 2 ksteps)
  const bf16* qbase = Q + ((size_t)b * S + q0 + w * 32 + lm) * U + h * DH + hi * 8;
  bf16x8 aq[2][2];
#pragma unroll
  for (int qm = 0; qm < 2; ++qm)
#pragma unroll
    for (int ks = 0; ks < 2; ++ks) {
      bf16x8 v = *reinterpret_cast<const bf16x8*>(qbase + (size_t)qm * 16 * U + ks * 32);
#pragma unroll
      for (int j = 0; j < 8; ++j) v[j] = (bf16)((float)v[j] * qscale);
      aq[qm][ks] = v;
    }

  float m[2][4], l[2][4];
  f32x4 o[2][4];
#pragma unroll
  for (int qm = 0; qm < 2; ++qm)
#pragma unroll
    for (int r = 0; r < 4; ++r) { m[qm][r] = -3e38f; l[qm][r] = 0.f; }
#pragma unroll
  for (int qm = 0; qm < 2; ++qm)
#pragma unroll
    for (int d = 0; d < 4; ++d) o[qm][d] = f32x4{0.f, 0.f, 0.f, 0.f};

  const bf16* kb0 = K + ((size_t)b * S + lm) * U + h * DH + hi * 8;
  const bf16* vb0 = Vt + ((size_t)bh * DH + lm) * S + hi * 8;

  for (int kt = 0; kt < S; kt += 64) {
    // ---- K fragments direct from L2 ----
    bf16x8 bk[2][4];
#pragma unroll
    for (int ni = 0; ni < 4; ++ni)
#pragma unroll
      for (int ks = 0; ks < 2; ++ks)
        bk[ks][ni] = *reinterpret_cast<const bf16x8*>(kb0 + (size_t)(kt + ni * 16) * U + ks * 32);

    // ---- S = Q K^T (pre-scaled, log2 domain). C: row=q (hi*4+r), col=key (ni*16+lm)
    f32x4 sA[2][4];
#pragma unroll
    for (int qm = 0; qm < 2; ++qm)
#pragma unroll
      for (int ni = 0; ni < 4; ++ni) sA[qm][ni] = f32x4{0.f, 0.f, 0.f, 0.f};
#pragma unroll
    for (int ks = 0; ks < 2; ++ks)
#pragma unroll
      for (int ni = 0; ni < 4; ++ni) {
        sA[0][ni] = __builtin_amdgcn_mfma_f32_16x16x32_bf16(aq[0][ks], bk[ks][ni], sA[0][ni], 0, 0, 0);
        sA[1][ni] = __builtin_amdgcn_mfma_f32_16x16x32_bf16(aq[1][ks], bk[ks][ni], sA[1][ni], 0, 0, 0);
      }

    // ---- row max ----
    float pm[2][4];
#pragma unroll
    for (int qm = 0; qm < 2; ++qm) {
#pragma unroll
      for (int r = 0; r < 4; ++r)
        pm[qm][r] = fmaxf(fmaxf(sA[qm][0][r], sA[qm][1][r]), fmaxf(sA[qm][2][r], sA[qm][3][r]));
#pragma unroll
      for (int msk = 1; msk < 16; msk <<= 1)
#pragma unroll
        for (int r = 0; r < 4; ++r)
          pm[qm][r] = fmaxf(pm[qm][r], __shfl_xor(pm[qm][r], msk));
    }

    // ---- defer-max rescale (skip O-rescale when max grew < 8 in log2 domain) ----
    bool okl = true;
#pragma unroll
    for (int qm = 0; qm < 2; ++qm)
#pragma unroll
      for (int r = 0; r < 4; ++r) okl &= (pm[qm][r] <= m[qm][r] + 8.f);
    if (!__all(okl)) {
#pragma unroll
      for (int qm = 0; qm < 2; ++qm)
#pragma unroll
        for (int r = 0; r < 4; ++r) {
          const float mn = fmaxf(m[qm][r], pm[qm][r]);
          const float f = fexp2(m[qm][r] - mn);
          m[qm][r] = mn;
          l[qm][r] *= f;
#pragma unroll
          for (int d = 0; d < 4; ++d) o[qm][d][r] *= f;
        }
    }

    // ---- P = exp2(S - m), row-sum, store to swizzled LDS ----
#pragma unroll
    for (int qm = 0; qm < 2; ++qm) {
      float ps[4] = {0.f, 0.f, 0.f, 0.f};
#pragma unroll
      for (int ni = 0; ni < 4; ++ni)
#pragma unroll
        for (int r = 0; r < 4; ++r) {
          const float p = fexp2(sA[qm][ni][r] - m[qm][r]);
          ps[r] += p;
          const int row = hi * 4 + r;
          char* pw = &Ps[w][qm][(row * 128 + (ni * 16 + lm) * 2) ^ ((row & 7) << 4)];
          *reinterpret_cast<bf16*>(pw) = (bf16)p;
        }
#pragma unroll
      for (int msk = 1; msk < 16; msk <<= 1)
#pragma unroll
        for (int r = 0; r < 4; ++r) ps[r] += __shfl_xor(ps[r], msk);
#pragma unroll
      for (int r = 0; r < 4; ++r) l[qm][r] += ps[r];
    }

    // ---- V fragments + O += P V. C: row=q (hi*4+r), col=d (dblk*16+lm) ----
    bf16x8 bv[2][4];
#pragma unroll
    for (int dblk = 0; dblk < 4; ++dblk)
#pragma unroll
      for (int ks = 0; ks < 2; ++ks)
        bv[ks][dblk] = *reinterpret_cast<const bf16x8*>(vb0 + (size_t)dblk * 16 * S + kt + ks * 32);

#pragma unroll
    for (int qm = 0; qm < 2; ++qm)
#pragma unroll
      for (int ks = 0; ks < 2; ++ks) {
        const bf16x8 ap = *reinterpret_cast<const bf16x8*>(
            &Ps[w][qm][(lm * 128 + ks * 64 + hi * 16) ^ ((lm & 7) << 4)]);
#pragma unroll
        for (int dblk = 0; dblk < 4; ++dblk)
          o[qm][dblk] = __builtin_amdgcn_mfma_f32_16x16x32_bf16(ap, bv[ks][dblk], o[qm][dblk], 0, 0, 0);
      }
  }

  // ---- normalize + store ----
#pragma unroll
  for (int qm = 0; qm < 2; ++qm)
#pragma unroll
    for (int r = 0; r < 4; ++r) {
      const float rl = 1.f / l[qm][r];
#pragma unroll
      for (int dblk = 0; dblk < 4; ++dblk) {
        const float v = o[qm][dblk][r] * rl;
        att[((size_t)b * S + q0 + w * 32 + qm * 16 + hi * 4 + r) * U + h * DH + dblk * 16 + lm] = (bf16)v;
      }
    }
}

// ---------- epilogue: x = relu(att + vres); LayerNorm(x)*gamma + beta ----------
__global__ __launch_bounds__(256) void ln_kernel(
    const bf16* __restrict__ att, const bf16* __restrict__ vres,
    const float* __restrict__ gamma, const float* __restrict__ beta,
    float* __restrict__ out) {
  const int row = blockIdx.x;
  const int t = threadIdx.x;
  const bf16* ar = att + (size_t)row * U;
  const bf16* vr = vres + (size_t)row * U;
  const bf16x4 av = *reinterpret_cast<const bf16x4*>(ar + t * 4);
  const bf16x4 vv = *reinterpret_cast<const bf16x4*>(vr + t * 4);
  float x[4];
  float sum = 0.f, sq = 0.f;
#pragma unroll
  for (int i = 0; i < 4; ++i) {
    x[i] = fmaxf((float)av[i] + (float)vv[i], 0.f);
    sum += x[i];
    sq += x[i] * x[i];
  }
#pragma unroll
  for (int mm = 1; mm < 64; mm <<= 1) {
    sum += __shfl_xor(sum, mm);
    sq  += __shfl_xor(sq, mm);
  }
  __shared__ float s1[4], s2[4];
  if ((t & 63) == 0) { s1[t >> 6] = sum; s2[t >> 6] = sq; }
  __syncthreads();
  sum = s1[0] + s1[1] + s1[2] + s1[3];
  sq  = s2[0] + s2[1] + s2[2] + s2[3];
  const float mean = sum * (1.f / U);
  float var = sq * (1.f / U) - mean * mean;
  var = fmaxf(var, 0.f);
  const float inv = rsqrtf(var + 1e-8f);
#pragma unroll
  for (int i = 0; i < 4; ++i) {
    const int c = t * 4 + i;
    out[(size_t)row * U + c] = gamma[c] * ((x[i] - mean) * inv) + beta[c];
  }
}

extern "C" void kernel_launch(void* const* d_in, const int* in_sizes, int n_in,
                              void* d_out, int out_size, void* d_ws, size_t ws_size,
                              hipStream_t stream) {
  const float* queries = (const float*)d_in[0];
  const float* keys    = (const float*)d_in[1];
  const float* values  = (const float*)d_in[2];
  const float* Wq = (const float*)d_in[3];
  const float* bq = (const float*)d_in[4];
  const float* Wk = (const float*)d_in[5];
  const float* bk = (const float*)d_in[6];
  const float* Wv = (const float*)d_in[7];
  const float* bv = (const float*)d_in[8];
  const float* Wr = (const float*)d_in[9];
  const float* br = (const float*)d_in[10];
  const float* gamma = (const float*)d_in[11];
  const float* beta  = (const float*)d_in[12];
  float* out = (float*)d_out;

  char* ws = (char*)d_ws;
  const size_t MB = 1024 * 1024;
  bf16* wqt = (bf16*)(ws + 0 * MB);
  bf16* wkt = (bf16*)(ws + 2 * MB);
  bf16* wvt = (bf16*)(ws + 4 * MB);
  bf16* wrt = (bf16*)(ws + 6 * MB);
  bf16* Xb  = (bf16*)(ws + 8 * MB);    // 16 MB, reused; becomes Vt after gemms
  bf16* Qb  = (bf16*)(ws + 24 * MB);
  bf16* Kb  = (bf16*)(ws + 40 * MB);
  bf16* Vb  = (bf16*)(ws + 56 * MB);
  bf16* Rb  = (bf16*)(ws + 72 * MB);
  bf16* attb= (bf16*)(ws + 88 * MB);   // total 104 MB
  bf16* Vtb = Xb;

  const int cvtBlocks = MTOT * U / (256 * 8);  // 4096

  transpose_w_kernel<<<dim3(32, 32, 4), dim3(32, 8), 0, stream>>>(
      Wq, Wk, Wv, Wr, wqt, wkt, wvt, wrt);
  xcvt_kernel<<<cvtBlocks, 256, 0, stream>>>(queries, Xb);
  gemm_kernel<<<dim3(8, 64), 256, 0, stream>>>(Xb, wqt, bq, Qb);
  xcvt_kernel<<<cvtBlocks, 256, 0, stream>>>(keys, Xb);
  gemm_kernel<<<dim3(8, 64), 256, 0, stream>>>(Xb, wkt, bk, Kb);
  xcvt_kernel<<<cvtBlocks, 256, 0, stream>>>(values, Xb);
  gemm_kernel<<<dim3(8, 64), 256, 0, stream>>>(Xb, wvt, bv, Vb);
  gemm_kernel<<<dim3(8, 64), 256, 0, stream>>>(Xb, wrt, br, Rb);
  transpose_v_kernel<<<dim3(64, 2, 64), dim3(32, 8), 0, stream>>>(Vb, Vtb);
  attn_kernel<<<dim3(1024), dim3(256), 0, stream>>>(Qb, Kb, Vtb, attb);
  ln_kernel<<<dim3(MTOT), dim3(256), 0, stream>>>(attb, Rb, gamma, beta, out);
}

// Round 3
// 402.217 us; speedup vs baseline: 1.0183x; 1.0029x over previous
//
#include <hip/hip_runtime.h>

constexpr int B = 4, S = 2048, U = 1024, H = 16, DH = 64;
constexpr int MTOT = B * S;

using bf16   = __bf16;
using f32x4  = __attribute__((ext_vector_type(4))) float;
using f32x16 = __attribute__((ext_vector_type(16))) float;
using bf16x8 = __attribute__((ext_vector_type(8))) bf16;
using bf16x4 = __attribute__((ext_vector_type(4))) bf16;
using u32x4  = __attribute__((ext_vector_type(4))) unsigned int;

__device__ __forceinline__ void gload16(const bf16* g, bf16* l) {
  __builtin_amdgcn_global_load_lds(
      (const __attribute__((address_space(1))) unsigned int*)g,
      (__attribute__((address_space(3))) unsigned int*)l, 16, 0, 0);
}

__device__ __forceinline__ float fexp2(float x) {
#if __has_builtin(__builtin_amdgcn_exp2f)
  return __builtin_amdgcn_exp2f(x);
#else
  return __expf(x * 0.6931471805599453f);
#endif
}

__device__ __forceinline__ f32x16 mfma32(bf16x8 a, bf16x8 b, f32x16 c) {
  return __builtin_amdgcn_mfma_f32_32x32x16_bf16(a, b, c, 0, 0, 0);
}

__device__ __forceinline__ unsigned packbf(float a, float b) {
  union { bf16 h; unsigned short s; } ua, ub;
  ua.h = (bf16)a; ub.h = (bf16)b;
  return ((unsigned)ub.s << 16) | (unsigned)ua.s;
}

// ---------- weight transpose + convert: Wt[n][k] = (bf16) W[k][n] ----------
__global__ void transpose_w_kernel(const float* __restrict__ w0, const float* __restrict__ w1,
                                   const float* __restrict__ w2, const float* __restrict__ w3,
                                   bf16* __restrict__ t0, bf16* __restrict__ t1,
                                   bf16* __restrict__ t2, bf16* __restrict__ t3) {
  const float* W = blockIdx.z == 0 ? w0 : blockIdx.z == 1 ? w1 : blockIdx.z == 2 ? w2 : w3;
  bf16* Wt       = blockIdx.z == 0 ? t0 : blockIdx.z == 1 ? t1 : blockIdx.z == 2 ? t2 : t3;
  __shared__ float tile[32][33];
  const int k0 = blockIdx.x * 32, n0 = blockIdx.y * 32;
  const int tx = threadIdx.x, ty = threadIdx.y;
  for (int i = ty; i < 32; i += 8) tile[i][tx] = W[(size_t)(k0 + i) * U + n0 + tx];
  __syncthreads();
  for (int i = ty; i < 32; i += 8) Wt[(size_t)(n0 + i) * U + k0 + tx] = (bf16)tile[tx][i];
}

// ---------- fp32 -> bf16 convert ----------
__global__ __launch_bounds__(256) void xcvt_kernel(const float* __restrict__ x, bf16* __restrict__ o) {
  const size_t i = ((size_t)blockIdx.x * 256 + threadIdx.x) * 8;
  const float4 v0 = *reinterpret_cast<const float4*>(x + i);
  const float4 v1 = *reinterpret_cast<const float4*>(x + i + 4);
  bf16x8 r;
  r[0] = (bf16)v0.x; r[1] = (bf16)v0.y; r[2] = (bf16)v0.z; r[3] = (bf16)v0.w;
  r[4] = (bf16)v1.x; r[5] = (bf16)v1.y; r[6] = (bf16)v1.z; r[7] = (bf16)v1.w;
  *reinterpret_cast<bf16x8*>(o + i) = r;
}

// ---------- GEMM: out = relu(A @ Wt^T + b), A bf16 [M][U], Wt bf16 [n][k] ----------
__global__ __launch_bounds__(256) void gemm_kernel(
    const bf16* __restrict__ A, const bf16* __restrict__ Wt,
    const float* __restrict__ bias, bf16* __restrict__ out) {
  const int bn = blockIdx.x * 128, bm = blockIdx.y * 128;
  const int t = threadIdx.x, lane = t & 63, wid = t >> 6;
  const int wr = wid >> 1, wc = wid & 1;
  const int lm = lane & 15, hi = lane >> 4;

  __shared__ __align__(16) bf16 As[128][32];
  __shared__ __align__(16) bf16 Bs[128][32];

  f32x4 acc[4][4];
#pragma unroll
  for (int i = 0; i < 4; ++i)
#pragma unroll
    for (int j = 0; j < 4; ++j) acc[i][j] = f32x4{0.f, 0.f, 0.f, 0.f};

  const int srow = wid * 32 + (lane >> 2);
  const int scol = (lane & 3) * 8;
  const bf16* ga = A  + (size_t)(bm + srow) * U + scol;
  const bf16* gb = Wt + (size_t)(bn + srow) * U + scol;
  bf16* lA0 = &As[wid * 32][0];
  bf16* lA1 = &As[wid * 32 + 16][0];
  bf16* lB0 = &Bs[wid * 32][0];
  bf16* lB1 = &Bs[wid * 32 + 16][0];

  for (int k0 = 0; k0 < U; k0 += 32) {
    __syncthreads();
    gload16(ga + k0, lA0);
    gload16(ga + (size_t)16 * U + k0, lA1);
    gload16(gb + k0, lB0);
    gload16(gb + (size_t)16 * U + k0, lB1);
    __syncthreads();

    bf16x8 a[4], bb[4];
#pragma unroll
    for (int mi = 0; mi < 4; ++mi)
      a[mi] = *reinterpret_cast<const bf16x8*>(&As[wr * 64 + mi * 16 + lm][hi * 8]);
#pragma unroll
    for (int ni = 0; ni < 4; ++ni)
      bb[ni] = *reinterpret_cast<const bf16x8*>(&Bs[wc * 64 + ni * 16 + lm][hi * 8]);
#pragma unroll
    for (int mi = 0; mi < 4; ++mi)
#pragma unroll
      for (int ni = 0; ni < 4; ++ni)
        acc[mi][ni] = __builtin_amdgcn_mfma_f32_16x16x32_bf16(a[mi], bb[ni], acc[mi][ni], 0, 0, 0);
  }

  const int mb = bm + wr * 64 + hi * 4;
  const int nb = bn + wc * 64 + lm;
#pragma unroll
  for (int ni = 0; ni < 4; ++ni) {
    const float bv_ = bias[nb + ni * 16];
#pragma unroll
    for (int mi = 0; mi < 4; ++mi)
#pragma unroll
      for (int r = 0; r < 4; ++r) {
        float vv = acc[mi][ni][r] + bv_;
        vv = fmaxf(vv, 0.f);
        out[(size_t)(mb + mi * 16 + r) * U + nb + ni * 16] = (bf16)vv;
      }
  }
}

// ---------- V transpose per head: Vt[(b*H+h)*DH + d][s] = V[b*S + s][h*DH + d] ----------
__global__ void transpose_v_kernel(const bf16* __restrict__ V, bf16* __restrict__ Vt) {
  __shared__ bf16 tile[32][33];
  const int bh = blockIdx.z;
  const int b = bh >> 4, h = bh & 15;
  const int s0 = blockIdx.x * 32, d0 = blockIdx.y * 32;
  const int tx = threadIdx.x, ty = threadIdx.y;
  for (int i = ty; i < 32; i += 8)
    tile[i][tx] = V[((size_t)b * S + s0 + i) * U + h * DH + d0 + tx];
  __syncthreads();
  for (int i = ty; i < 32; i += 8)
    Vt[((size_t)bh * DH + d0 + i) * S + s0 + tx] = tile[tx][i];
}

// ---------- flash attention: swapped QK^T (32x32x16), in-register softmax ----------
// Per wave: 32 q-rows. S^T[k][q] layout -> each lane owns the full key-row of
// one q (32 regs + partner lane^32). No LDS, no barriers.
__global__ __launch_bounds__(256) void attn_kernel(
    const bf16* __restrict__ Q, const bf16* __restrict__ K,
    const bf16* __restrict__ Vt, bf16* __restrict__ att) {
  const int bid = blockIdx.x;
  const int swz = (bid & 7) * 128 + (bid >> 3);     // 8 bh per XCD
  const int bh = swz >> 4, qx = swz & 15;
  const int b = bh >> 4, h = bh & 15;
  const int q0 = qx * 128 + (threadIdx.x >> 6) * 32;
  const int lane = threadIdx.x & 63;
  const int l31 = lane & 31, hi8 = lane >> 5;

  const float qscale = 0.18033688011111606f;  // log2(e)/sqrt(DH)

  // Q fragments (B operand: col = q = l31, contraction = dh)
  const bf16* qbase = Q + ((size_t)b * S + q0 + l31) * U + h * DH + hi8 * 8;
  bf16x8 qf[4];
#pragma unroll
  for (int ks = 0; ks < 4; ++ks) {
    bf16x8 v = *reinterpret_cast<const bf16x8*>(qbase + ks * 16);
#pragma unroll
    for (int j = 0; j < 8; ++j) v[j] = (bf16)((float)v[j] * qscale);
    qf[ks] = v;
  }

  float m = -3e38f, lsum = 0.f;
  f32x16 o0 = (f32x16)0.f, o1 = (f32x16)0.f;

  const bf16* kbase = K + ((size_t)b * S + l31) * U + h * DH + hi8 * 8;
  const bf16* vbase = Vt + ((size_t)bh * DH + l31) * S + hi8 * 8;

  for (int kt = 0; kt < S; kt += 64) {
    // K fragments (A operand: row = k)
    bf16x8 kf[2][4];
#pragma unroll
    for (int tt = 0; tt < 2; ++tt)
#pragma unroll
      for (int ks = 0; ks < 4; ++ks)
        kf[tt][ks] = *reinterpret_cast<const bf16x8*>(kbase + (size_t)(kt + tt * 32) * U + ks * 16);

    // S^T = K Q^T : rows = k (crow(r,hi8)), cols = q (l31)
    f32x16 s0 = (f32x16)0.f, s1 = (f32x16)0.f;
#pragma unroll
    for (int ks = 0; ks < 4; ++ks) {
      s0 = mfma32(kf[0][ks], qf[ks], s0);
      s1 = mfma32(kf[1][ks], qf[ks], s1);
    }

    // V fragments (B operand for PV; issued here so L2 latency hides under softmax)
    bf16x8 vf[2][4];
#pragma unroll
    for (int dt = 0; dt < 2; ++dt)
#pragma unroll
      for (int ks = 0; ks < 4; ++ks)
        vf[dt][ks] = *reinterpret_cast<const bf16x8*>(vbase + ((size_t)dt * 32) * S + kt + ks * 16);

    // in-lane max over own 32 keys (tree), then merge with partner lane^32
    float mx8[8];
#pragma unroll
    for (int i = 0; i < 8; ++i)
      mx8[i] = fmaxf(fmaxf(s0[i], s0[i + 8]), fmaxf(s1[i], s1[i + 8]));
    float mx = fmaxf(fmaxf(fmaxf(mx8[0], mx8[1]), fmaxf(mx8[2], mx8[3])),
                     fmaxf(fmaxf(mx8[4], mx8[5]), fmaxf(mx8[6], mx8[7])));
    mx = fmaxf(mx, __shfl_xor(mx, 32));

    // defer-max: rescale only when max grew > 8 (log2 domain) for any lane
    if (__any(mx > m + 8.f)) {
      const float mn = fmaxf(m, mx);
      const float f = fexp2(m - mn);
      m = mn;
      lsum *= f;
#pragma unroll
      for (int r = 0; r < 16; ++r) {
        const float fr = __shfl(f, (r & 3) + 8 * (r >> 2) + 4 * hi8);
        o0[r] *= fr;
        o1[r] *= fr;
      }
    }

    // P = exp2(S - m): all 32 values lane-local; pack to bf16 pairs
    unsigned wpk[16], owpk[16];
    float ps0 = 0.f, ps1 = 0.f, ps2 = 0.f, ps3 = 0.f;
#pragma unroll
    for (int i = 0; i < 8; ++i) {
      const float pa = fexp2(s0[2 * i] - m);
      const float pb = fexp2(s0[2 * i + 1] - m);
      ps0 += pa; ps1 += pb;
      wpk[i] = packbf(pa, pb);
      const float pc = fexp2(s1[2 * i] - m);
      const float pd = fexp2(s1[2 * i + 1] - m);
      ps2 += pc; ps3 += pd;
      wpk[8 + i] = packbf(pc, pd);
    }
    float ps = (ps0 + ps1) + (ps2 + ps3);
    ps += __shfl_xor(ps, 32);
    lsum += ps;

    // exchange halves with partner lane (rows 4..7 mod 8 live there)
#pragma unroll
    for (int i = 0; i < 16; ++i) owpk[i] = __shfl_xor(wpk[i], 32);

    // assemble A-fragments of P for PV (row = q ... wait: row = k? no: A = P[q][k])
    // fw[ks] covers contraction k = kt + ks*16 + hi8*8 + j for this lane's q
    u32x4 fw[4];
    fw[0] = hi8 ? u32x4{owpk[2], owpk[3], wpk[2], wpk[3]}
                : u32x4{wpk[0], wpk[1], owpk[0], owpk[1]};
    fw[1] = hi8 ? u32x4{owpk[6], owpk[7], wpk[6], wpk[7]}
                : u32x4{wpk[4], wpk[5], owpk[4], owpk[5]};
    fw[2] = hi8 ? u32x4{owpk[10], owpk[11], wpk[10], wpk[11]}
                : u32x4{wpk[8], wpk[9], owpk[8], owpk[9]};
    fw[3] = hi8 ? u32x4{owpk[14], owpk[15], wpk[14], wpk[15]}
                : u32x4{wpk[12], wpk[13], owpk[12], owpk[13]};

    // O += P V : rows = q (crow), cols = d (dtile*32 + l31)
#pragma unroll
    for (int ks = 0; ks < 4; ++ks) {
      const bf16x8 pf = __builtin_bit_cast(bf16x8, fw[ks]);
      o0 = mfma32(pf, vf[0][ks], o0);
      o1 = mfma32(pf, vf[1][ks], o1);
    }
  }

  // normalize (1/lsum lives at lane q; bpermute per output row) + store
  const float linv = 1.f / lsum;
  bf16* obase = att + ((size_t)b * S + q0) * U + h * DH + l31;
#pragma unroll
  for (int r = 0; r < 16; ++r) {
    const int row = (r & 3) + 8 * (r >> 2) + 4 * hi8;
    const float lr = __shfl(linv, row);
    obase[(size_t)row * U]      = (bf16)(o0[r] * lr);
    obase[(size_t)row * U + 32] = (bf16)(o1[r] * lr);
  }
}

// ---------- epilogue: x = relu(att + vres); LayerNorm(x)*gamma + beta ----------
__global__ __launch_bounds__(256) void ln_kernel(
    const bf16* __restrict__ att, const bf16* __restrict__ vres,
    const float* __restrict__ gamma, const float* __restrict__ beta,
    float* __restrict__ out) {
  const int row = blockIdx.x;
  const int t = threadIdx.x;
  const bf16* ar = att + (size_t)row * U;
  const bf16* vr = vres + (size_t)row * U;
  const bf16x4 av = *reinterpret_cast<const bf16x4*>(ar + t * 4);
  const bf16x4 vv = *reinterpret_cast<const bf16x4*>(vr + t * 4);
  float x[4];
  float sum = 0.f, sq = 0.f;
#pragma unroll
  for (int i = 0; i < 4; ++i) {
    x[i] = fmaxf((float)av[i] + (float)vv[i], 0.f);
    sum += x[i];
    sq += x[i] * x[i];
  }
#pragma unroll
  for (int mm = 1; mm < 64; mm <<= 1) {
    sum += __shfl_xor(sum, mm);
    sq  += __shfl_xor(sq, mm);
  }
  __shared__ float s1[4], s2[4];
  if ((t & 63) == 0) { s1[t >> 6] = sum; s2[t >> 6] = sq; }
  __syncthreads();
  sum = s1[0] + s1[1] + s1[2] + s1[3];
  sq  = s2[0] + s2[1] + s2[2] + s2[3];
  const float mean = sum * (1.f / U);
  float var = sq * (1.f / U) - mean * mean;
  var = fmaxf(var, 0.f);
  const float inv = rsqrtf(var + 1e-8f);
#pragma unroll
  for (int i = 0; i < 4; ++i) {
    const int c = t * 4 + i;
    out[(size_t)row * U + c] = gamma[c] * ((x[i] - mean) * inv) + beta[c];
  }
}

extern "C" void kernel_launch(void* const* d_in, const int* in_sizes, int n_in,
                              void* d_out, int out_size, void* d_ws, size_t ws_size,
                              hipStream_t stream) {
  const float* queries = (const float*)d_in[0];
  const float* keys    = (const float*)d_in[1];
  const float* values  = (const float*)d_in[2];
  const float* Wq = (const float*)d_in[3];
  const float* bq = (const float*)d_in[4];
  const float* Wk = (const float*)d_in[5];
  const float* bk = (const float*)d_in[6];
  const float* Wv = (const float*)d_in[7];
  const float* bv = (const float*)d_in[8];
  const float* Wr = (const float*)d_in[9];
  const float* br = (const float*)d_in[10];
  const float* gamma = (const float*)d_in[11];
  const float* beta  = (const float*)d_in[12];
  float* out = (float*)d_out;

  char* ws = (char*)d_ws;
  const size_t MB = 1024 * 1024;
  bf16* wqt = (bf16*)(ws + 0 * MB);
  bf16* wkt = (bf16*)(ws + 2 * MB);
  bf16* wvt = (bf16*)(ws + 4 * MB);
  bf16* wrt = (bf16*)(ws + 6 * MB);
  bf16* Xb  = (bf16*)(ws + 8 * MB);    // 16 MB, reused; becomes Vt after gemms
  bf16* Qb  = (bf16*)(ws + 24 * MB);
  bf16* Kb  = (bf16*)(ws + 40 * MB);
  bf16* Vb  = (bf16*)(ws + 56 * MB);
  bf16* Rb  = (bf16*)(ws + 72 * MB);
  bf16* attb= (bf16*)(ws + 88 * MB);   // total 104 MB
  bf16* Vtb = Xb;

  const int cvtBlocks = MTOT * U / (256 * 8);  // 4096

  transpose_w_kernel<<<dim3(32, 32, 4), dim3(32, 8), 0, stream>>>(
      Wq, Wk, Wv, Wr, wqt, wkt, wvt, wrt);
  xcvt_kernel<<<cvtBlocks, 256, 0, stream>>>(queries, Xb);
  gemm_kernel<<<dim3(8, 64), 256, 0, stream>>>(Xb, wqt, bq, Qb);
  xcvt_kernel<<<cvtBlocks, 256, 0, stream>>>(keys, Xb);
  gemm_kernel<<<dim3(8, 64), 256, 0, stream>>>(Xb, wkt, bk, Kb);
  xcvt_kernel<<<cvtBlocks, 256, 0, stream>>>(values, Xb);
  gemm_kernel<<<dim3(8, 64), 256, 0, stream>>>(Xb, wvt, bv, Vb);
  gemm_kernel<<<dim3(8, 64), 256, 0, stream>>>(Xb, wrt, br, Rb);
  transpose_v_kernel<<<dim3(64, 2, 64), dim3(32, 8), 0, stream>>>(Vb, Vtb);
  attn_kernel<<<dim3(1024), dim3(256), 0, stream>>>(Qb, Kb, Vtb, attb);
  ln_kernel<<<dim3(MTOT), dim3(256), 0, stream>>>(attb, Rb, gamma, beta, out);
}

// Round 4
// 313.079 us; speedup vs baseline: 1.3082x; 1.2847x over previous
//
#include <hip/hip_runtime.h>

constexpr int B = 4, S = 2048, U = 1024, H = 16, DH = 64;
constexpr int MTOT = B * S;
constexpr int NT = S / 64;   // 32 key-tiles of 64

using bf16   = __bf16;
using f32x4  = __attribute__((ext_vector_type(4))) float;
using f32x16 = __attribute__((ext_vector_type(16))) float;
using bf16x8 = __attribute__((ext_vector_type(8))) bf16;
using bf16x4 = __attribute__((ext_vector_type(4))) bf16;
using u32x4  = __attribute__((ext_vector_type(4))) unsigned int;

__device__ __forceinline__ void gload16(const bf16* g, bf16* l) {
  __builtin_amdgcn_global_load_lds(
      (const __attribute__((address_space(1))) unsigned int*)g,
      (__attribute__((address_space(3))) unsigned int*)l, 16, 0, 0);
}

__device__ __forceinline__ float fexp2(float x) {
#if __has_builtin(__builtin_amdgcn_exp2f)
  return __builtin_amdgcn_exp2f(x);
#else
  return __expf(x * 0.6931471805599453f);
#endif
}

__device__ __forceinline__ f32x16 mfma32(bf16x8 a, bf16x8 b, f32x16 c) {
  return __builtin_amdgcn_mfma_f32_32x32x16_bf16(a, b, c, 0, 0, 0);
}

__device__ __forceinline__ unsigned packbf(float a, float b) {
  union { bf16 h; unsigned short s; } ua, ub;
  ua.h = (bf16)a; ub.h = (bf16)b;
  return ((unsigned)ub.s << 16) | (unsigned)ua.s;
}

// ---------- weight transpose + convert: Wt[n][k] = (bf16) W[k][n] ----------
__global__ void transpose_w_kernel(const float* __restrict__ w0, const float* __restrict__ w1,
                                   const float* __restrict__ w2, const float* __restrict__ w3,
                                   bf16* __restrict__ t0, bf16* __restrict__ t1,
                                   bf16* __restrict__ t2, bf16* __restrict__ t3) {
  const float* W = blockIdx.z == 0 ? w0 : blockIdx.z == 1 ? w1 : blockIdx.z == 2 ? w2 : w3;
  bf16* Wt       = blockIdx.z == 0 ? t0 : blockIdx.z == 1 ? t1 : blockIdx.z == 2 ? t2 : t3;
  __shared__ float tile[32][33];
  const int k0 = blockIdx.x * 32, n0 = blockIdx.y * 32;
  const int tx = threadIdx.x, ty = threadIdx.y;
  for (int i = ty; i < 32; i += 8) tile[i][tx] = W[(size_t)(k0 + i) * U + n0 + tx];
  __syncthreads();
  for (int i = ty; i < 32; i += 8) Wt[(size_t)(n0 + i) * U + k0 + tx] = (bf16)tile[tx][i];
}

// ---------- fp32 -> bf16 convert ----------
__global__ __launch_bounds__(256) void xcvt_kernel(const float* __restrict__ x, bf16* __restrict__ o) {
  const size_t i = ((size_t)blockIdx.x * 256 + threadIdx.x) * 8;
  const float4 v0 = *reinterpret_cast<const float4*>(x + i);
  const float4 v1 = *reinterpret_cast<const float4*>(x + i + 4);
  bf16x8 r;
  r[0] = (bf16)v0.x; r[1] = (bf16)v0.y; r[2] = (bf16)v0.z; r[3] = (bf16)v0.w;
  r[4] = (bf16)v1.x; r[5] = (bf16)v1.y; r[6] = (bf16)v1.z; r[7] = (bf16)v1.w;
  *reinterpret_cast<bf16x8*>(o + i) = r;
}

// ---------- GEMM: out = relu(A @ Wt^T + b), A bf16 [M][U], Wt bf16 [n][k] ----------
__global__ __launch_bounds__(256) void gemm_kernel(
    const bf16* __restrict__ A, const bf16* __restrict__ Wt,
    const float* __restrict__ bias, bf16* __restrict__ out) {
  const int bn = blockIdx.x * 128, bm = blockIdx.y * 128;
  const int t = threadIdx.x, lane = t & 63, wid = t >> 6;
  const int wr = wid >> 1, wc = wid & 1;
  const int lm = lane & 15, hi = lane >> 4;

  __shared__ __align__(16) bf16 As[128][32];
  __shared__ __align__(16) bf16 Bs[128][32];

  f32x4 acc[4][4];
#pragma unroll
  for (int i = 0; i < 4; ++i)
#pragma unroll
    for (int j = 0; j < 4; ++j) acc[i][j] = f32x4{0.f, 0.f, 0.f, 0.f};

  const int srow = wid * 32 + (lane >> 2);
  const int scol = (lane & 3) * 8;
  const bf16* ga = A  + (size_t)(bm + srow) * U + scol;
  const bf16* gb = Wt + (size_t)(bn + srow) * U + scol;
  bf16* lA0 = &As[wid * 32][0];
  bf16* lA1 = &As[wid * 32 + 16][0];
  bf16* lB0 = &Bs[wid * 32][0];
  bf16* lB1 = &Bs[wid * 32 + 16][0];

  for (int k0 = 0; k0 < U; k0 += 32) {
    __syncthreads();
    gload16(ga + k0, lA0);
    gload16(ga + (size_t)16 * U + k0, lA1);
    gload16(gb + k0, lB0);
    gload16(gb + (size_t)16 * U + k0, lB1);
    __syncthreads();

    bf16x8 a[4], bb[4];
#pragma unroll
    for (int mi = 0; mi < 4; ++mi)
      a[mi] = *reinterpret_cast<const bf16x8*>(&As[wr * 64 + mi * 16 + lm][hi * 8]);
#pragma unroll
    for (int ni = 0; ni < 4; ++ni)
      bb[ni] = *reinterpret_cast<const bf16x8*>(&Bs[wc * 64 + ni * 16 + lm][hi * 8]);
#pragma unroll
    for (int mi = 0; mi < 4; ++mi)
#pragma unroll
      for (int ni = 0; ni < 4; ++ni)
        acc[mi][ni] = __builtin_amdgcn_mfma_f32_16x16x32_bf16(a[mi], bb[ni], acc[mi][ni], 0, 0, 0);
  }

  const int mb = bm + wr * 64 + hi * 4;
  const int nb = bn + wc * 64 + lm;
#pragma unroll
  for (int ni = 0; ni < 4; ++ni) {
    const float bv_ = bias[nb + ni * 16];
#pragma unroll
    for (int mi = 0; mi < 4; ++mi)
#pragma unroll
      for (int r = 0; r < 4; ++r) {
        float vv = acc[mi][ni][r] + bv_;
        vv = fmaxf(vv, 0.f);
        out[(size_t)(mb + mi * 16 + r) * U + nb + ni * 16] = (bf16)vv;
      }
  }
}

// ---------- V transpose per head: Vt[(b*H+h)*DH + d][s] = V[b*S + s][h*DH + d] ----------
__global__ void transpose_v_kernel(const bf16* __restrict__ V, bf16* __restrict__ Vt) {
  __shared__ bf16 tile[32][33];
  const int bh = blockIdx.z;
  const int b = bh >> 4, h = bh & 15;
  const int s0 = blockIdx.x * 32, d0 = blockIdx.y * 32;
  const int tx = threadIdx.x, ty = threadIdx.y;
  for (int i = ty; i < 32; i += 8)
    tile[i][tx] = V[((size_t)b * S + s0 + i) * U + h * DH + d0 + tx];
  __syncthreads();
  for (int i = ty; i < 32; i += 8)
    Vt[((size_t)bh * DH + d0 + i) * S + s0 + tx] = tile[tx][i];
}

// ---------- pack K into fragment-major tiles ----------
// Kp[bh][t][tt][ks][lane][8] = K[b*S + t*64 + tt*32 + (lane&31)][h*64 + ks*16 + (lane>>5)*8 + j]
__global__ __launch_bounds__(256) void pack_k_kernel(const bf16* __restrict__ Kb, bf16* __restrict__ Kp) {
  const int blk = blockIdx.x;            // bh*32 + t
  const int bh = blk >> 5, t = blk & 31;
  const int b = bh >> 4, h = bh & 15;
  bf16* dst = Kp + (size_t)blk * 4096;   // 8KB tile
#pragma unroll
  for (int p = 0; p < 2; ++p) {
    const int c = p * 256 + threadIdx.x;           // chunk 0..511
    const int tt = c >> 8, ks = (c >> 6) & 3, ln = c & 63;
    const int l31 = ln & 31, hi = ln >> 5;
    const bf16* src = Kb + (size_t)(b * S + t * 64 + tt * 32 + l31) * U + h * DH + ks * 16 + hi * 8;
    *reinterpret_cast<int4*>(dst + c * 8) = *reinterpret_cast<const int4*>(src);
  }
}

// ---------- pack V (from Vt) into fragment-major tiles ----------
// Vp[bh][t][dt][ks][lane][8] = Vt[(bh*DH + dt*32 + (lane&31))*S + t*64 + ks*16 + (lane>>5)*8 + j]
__global__ __launch_bounds__(256) void pack_v_kernel(const bf16* __restrict__ Vt, bf16* __restrict__ Vp) {
  const int blk = blockIdx.x;
  const int bh = blk >> 5, t = blk & 31;
  bf16* dst = Vp + (size_t)blk * 4096;
#pragma unroll
  for (int p = 0; p < 2; ++p) {
    const int c = p * 256 + threadIdx.x;
    const int dt = c >> 8, ks = (c >> 6) & 3, ln = c & 63;
    const int l31 = ln & 31, hi = ln >> 5;
    const bf16* src = Vt + (size_t)(bh * DH + dt * 32 + l31) * S + t * 64 + ks * 16 + hi * 8;
    *reinterpret_cast<int4*>(dst + c * 8) = *reinterpret_cast<const int4*>(src);
  }
}

// ---------- flash attention: packed K/V tiles staged via global_load_lds ----------
// Swapped QK^T (32x32x16), in-register softmax; 4 waves share each 16KB tile.
__global__ __launch_bounds__(256) void attn_kernel(
    const bf16* __restrict__ Q, const bf16* __restrict__ Kp,
    const bf16* __restrict__ Vp, bf16* __restrict__ att) {
  const int bid = blockIdx.x;
  const int swz = (bid & 7) * 128 + (bid >> 3);     // 8 bh per XCD
  const int bh = swz >> 4, qx = swz & 15;
  const int b = bh >> 4, h = bh & 15;
  const int tid = threadIdx.x;
  const int q0 = qx * 128 + (tid >> 6) * 32;
  const int lane = tid & 63;
  const int l31 = lane & 31, hi8 = lane >> 5;

  __shared__ __align__(16) bf16 kbuf[2][4096];   // [tt][ks][lane][8] = 8KB
  __shared__ __align__(16) bf16 vbuf[2][4096];   // [dt][ks][lane][8] = 8KB

  const float qscale = 0.18033688011111606f;  // log2(e)/sqrt(DH)

  // Q fragments (B operand: col = q = l31, contraction = dh)
  const bf16* qbase = Q + ((size_t)b * S + q0 + l31) * U + h * DH + hi8 * 8;
  bf16x8 qf[4];
#pragma unroll
  for (int ks = 0; ks < 4; ++ks) {
    bf16x8 v = *reinterpret_cast<const bf16x8*>(qbase + ks * 16);
#pragma unroll
    for (int j = 0; j < 8; ++j) v[j] = (bf16)((float)v[j] * qscale);
    qf[ks] = v;
  }

  float m = -3e38f, lsum = 0.f;
  f32x16 o0 = (f32x16)0.f, o1 = (f32x16)0.f;

  const bf16* kpb = Kp + (size_t)bh * 32 * 4096;  // per-bh packed base
  const bf16* vpb = Vp + (size_t)bh * 32 * 4096;

  // stage tile 0
  {
    const bf16* ks0 = kpb;
    const bf16* vs0 = vpb;
#pragma unroll
    for (int p = 0; p < 2; ++p) {
      gload16(ks0 + (p * 256 + tid) * 8, &kbuf[0][(p * 256 + tid) * 8]);
      gload16(vs0 + (p * 256 + tid) * 8, &vbuf[0][(p * 256 + tid) * 8]);
    }
  }
  __syncthreads();

  for (int t = 0; t < NT; ++t) {
    const int cur = t & 1;
    // stage next tile into the other buffer
    if (t + 1 < NT) {
      const bf16* ksn = kpb + (size_t)(t + 1) * 4096;
      const bf16* vsn = vpb + (size_t)(t + 1) * 4096;
#pragma unroll
      for (int p = 0; p < 2; ++p) {
        gload16(ksn + (p * 256 + tid) * 8, &kbuf[cur ^ 1][(p * 256 + tid) * 8]);
        gload16(vsn + (p * 256 + tid) * 8, &vbuf[cur ^ 1][(p * 256 + tid) * 8]);
      }
    }

    // K fragments (A operand: row = k) from LDS, contiguous per lane
    bf16x8 kf[2][4];
#pragma unroll
    for (int tt = 0; tt < 2; ++tt)
#pragma unroll
      for (int ks = 0; ks < 4; ++ks)
        kf[tt][ks] = *reinterpret_cast<const bf16x8*>(&kbuf[cur][(tt * 4 + ks) * 512 + lane * 8]);

    // S^T = K Q^T : rows = k (crow(r,hi8)), cols = q (l31)
    f32x16 s0 = (f32x16)0.f, s1 = (f32x16)0.f;
#pragma unroll
    for (int ks = 0; ks < 4; ++ks) {
      s0 = mfma32(kf[0][ks], qf[ks], s0);
      s1 = mfma32(kf[1][ks], qf[ks], s1);
    }

    // V fragments (B operand for PV)
    bf16x8 vf[2][4];
#pragma unroll
    for (int dt = 0; dt < 2; ++dt)
#pragma unroll
      for (int ks = 0; ks < 4; ++ks)
        vf[dt][ks] = *reinterpret_cast<const bf16x8*>(&vbuf[cur][(dt * 4 + ks) * 512 + lane * 8]);

    // in-lane max over own 32 keys (tree), then merge with partner lane^32
    float mx8[8];
#pragma unroll
    for (int i = 0; i < 8; ++i)
      mx8[i] = fmaxf(fmaxf(s0[i], s0[i + 8]), fmaxf(s1[i], s1[i + 8]));
    float mx = fmaxf(fmaxf(fmaxf(mx8[0], mx8[1]), fmaxf(mx8[2], mx8[3])),
                     fmaxf(fmaxf(mx8[4], mx8[5]), fmaxf(mx8[6], mx8[7])));
    mx = fmaxf(mx, __shfl_xor(mx, 32));

    // defer-max: rescale only when max grew > 8 (log2 domain) for any lane
    if (__any(mx > m + 8.f)) {
      const float mn = fmaxf(m, mx);
      const float f = fexp2(m - mn);
      m = mn;
      lsum *= f;
#pragma unroll
      for (int r = 0; r < 16; ++r) {
        const float fr = __shfl(f, (r & 3) + 8 * (r >> 2) + 4 * hi8);
        o0[r] *= fr;
        o1[r] *= fr;
      }
    }

    // P = exp2(S - m): all 32 values lane-local; pack to bf16 pairs
    unsigned wpk[16], owpk[16];
    float ps0 = 0.f, ps1 = 0.f, ps2 = 0.f, ps3 = 0.f;
#pragma unroll
    for (int i = 0; i < 8; ++i) {
      const float pa = fexp2(s0[2 * i] - m);
      const float pb = fexp2(s0[2 * i + 1] - m);
      ps0 += pa; ps1 += pb;
      wpk[i] = packbf(pa, pb);
      const float pc = fexp2(s1[2 * i] - m);
      const float pd = fexp2(s1[2 * i + 1] - m);
      ps2 += pc; ps3 += pd;
      wpk[8 + i] = packbf(pc, pd);
    }
    float ps = (ps0 + ps1) + (ps2 + ps3);
    ps += __shfl_xor(ps, 32);
    lsum += ps;

    // exchange halves with partner lane (rows 4..7 mod 8 live there)
#pragma unroll
    for (int i = 0; i < 16; ++i) owpk[i] = __shfl_xor(wpk[i], 32);

    // assemble A-fragments of P for PV: fw[ks] covers k = ks*16 + hi8*8 + j
    u32x4 fw[4];
    fw[0] = hi8 ? u32x4{owpk[2], owpk[3], wpk[2], wpk[3]}
                : u32x4{wpk[0], wpk[1], owpk[0], owpk[1]};
    fw[1] = hi8 ? u32x4{owpk[6], owpk[7], wpk[6], wpk[7]}
                : u32x4{wpk[4], wpk[5], owpk[4], owpk[5]};
    fw[2] = hi8 ? u32x4{owpk[10], owpk[11], wpk[10], wpk[11]}
                : u32x4{wpk[8], wpk[9], owpk[8], owpk[9]};
    fw[3] = hi8 ? u32x4{owpk[14], owpk[15], wpk[14], wpk[15]}
                : u32x4{wpk[12], wpk[13], owpk[12], owpk[13]};

    // O += P V : rows = q (crow), cols = d (dtile*32 + l31)
#pragma unroll
    for (int ks = 0; ks < 4; ++ks) {
      const bf16x8 pf = __builtin_bit_cast(bf16x8, fw[ks]);
      o0 = mfma32(pf, vf[0][ks], o0);
      o1 = mfma32(pf, vf[1][ks], o1);
    }

    __syncthreads();   // staged loads drained (vmcnt0) + all waves done with cur
  }

  // normalize (1/lsum lives at lane q) + store
  const float linv = 1.f / lsum;
  bf16* obase = att + ((size_t)b * S + q0) * U + h * DH + l31;
#pragma unroll
  for (int r = 0; r < 16; ++r) {
    const int row = (r & 3) + 8 * (r >> 2) + 4 * hi8;
    const float lr = __shfl(linv, row);
    obase[(size_t)row * U]      = (bf16)(o0[r] * lr);
    obase[(size_t)row * U + 32] = (bf16)(o1[r] * lr);
  }
}

// ---------- epilogue: x = relu(att + vres); LayerNorm(x)*gamma + beta ----------
__global__ __launch_bounds__(256) void ln_kernel(
    const bf16* __restrict__ att, const bf16* __restrict__ vres,
    const float* __restrict__ gamma, const float* __restrict__ beta,
    float* __restrict__ out) {
  const int row = blockIdx.x;
  const int t = threadIdx.x;
  const bf16* ar = att + (size_t)row * U;
  const bf16* vr = vres + (size_t)row * U;
  const bf16x4 av = *reinterpret_cast<const bf16x4*>(ar + t * 4);
  const bf16x4 vv = *reinterpret_cast<const bf16x4*>(vr + t * 4);
  float x[4];
  float sum = 0.f, sq = 0.f;
#pragma unroll
  for (int i = 0; i < 4; ++i) {
    x[i] = fmaxf((float)av[i] + (float)vv[i], 0.f);
    sum += x[i];
    sq += x[i] * x[i];
  }
#pragma unroll
  for (int mm = 1; mm < 64; mm <<= 1) {
    sum += __shfl_xor(sum, mm);
    sq  += __shfl_xor(sq, mm);
  }
  __shared__ float s1[4], s2[4];
  if ((t & 63) == 0) { s1[t >> 6] = sum; s2[t >> 6] = sq; }
  __syncthreads();
  sum = s1[0] + s1[1] + s1[2] + s1[3];
  sq  = s2[0] + s2[1] + s2[2] + s2[3];
  const float mean = sum * (1.f / U);
  float var = sq * (1.f / U) - mean * mean;
  var = fmaxf(var, 0.f);
  const float inv = rsqrtf(var + 1e-8f);
#pragma unroll
  for (int i = 0; i < 4; ++i) {
    const int c = t * 4 + i;
    out[(size_t)row * U + c] = gamma[c] * ((x[i] - mean) * inv) + beta[c];
  }
}

extern "C" void kernel_launch(void* const* d_in, const int* in_sizes, int n_in,
                              void* d_out, int out_size, void* d_ws, size_t ws_size,
                              hipStream_t stream) {
  const float* queries = (const float*)d_in[0];
  const float* keys    = (const float*)d_in[1];
  const float* values  = (const float*)d_in[2];
  const float* Wq = (const float*)d_in[3];
  const float* bq = (const float*)d_in[4];
  const float* Wk = (const float*)d_in[5];
  const float* bk = (const float*)d_in[6];
  const float* Wv = (const float*)d_in[7];
  const float* bv = (const float*)d_in[8];
  const float* Wr = (const float*)d_in[9];
  const float* br = (const float*)d_in[10];
  const float* gamma = (const float*)d_in[11];
  const float* beta  = (const float*)d_in[12];
  float* out = (float*)d_out;

  char* ws = (char*)d_ws;
  const size_t MB = 1024 * 1024;
  bf16* wqt = (bf16*)(ws + 0 * MB);
  bf16* wkt = (bf16*)(ws + 2 * MB);
  bf16* wvt = (bf16*)(ws + 4 * MB);
  bf16* wrt = (bf16*)(ws + 6 * MB);
  bf16* Xb  = (bf16*)(ws + 8 * MB);    // 16 MB, reused; becomes Vt after gemms
  bf16* Qb  = (bf16*)(ws + 24 * MB);
  bf16* Kb  = (bf16*)(ws + 40 * MB);   // after pack_k becomes Vp
  bf16* Vb  = (bf16*)(ws + 56 * MB);   // after transpose_v becomes Kp
  bf16* Rb  = (bf16*)(ws + 72 * MB);
  bf16* attb= (bf16*)(ws + 88 * MB);   // total 104 MB
  bf16* Vtb = Xb;
  bf16* Kp  = Vb;    // Vb dead after transpose_v
  bf16* Vp  = Kb;    // Kb dead after pack_k

  const int cvtBlocks = MTOT * U / (256 * 8);  // 4096

  transpose_w_kernel<<<dim3(32, 32, 4), dim3(32, 8), 0, stream>>>(
      Wq, Wk, Wv, Wr, wqt, wkt, wvt, wrt);
  xcvt_kernel<<<cvtBlocks, 256, 0, stream>>>(queries, Xb);
  gemm_kernel<<<dim3(8, 64), 256, 0, stream>>>(Xb, wqt, bq, Qb);
  xcvt_kernel<<<cvtBlocks, 256, 0, stream>>>(keys, Xb);
  gemm_kernel<<<dim3(8, 64), 256, 0, stream>>>(Xb, wkt, bk, Kb);
  xcvt_kernel<<<cvtBlocks, 256, 0, stream>>>(values, Xb);
  gemm_kernel<<<dim3(8, 64), 256, 0, stream>>>(Xb, wvt, bv, Vb);
  gemm_kernel<<<dim3(8, 64), 256, 0, stream>>>(Xb, wrt, br, Rb);
  transpose_v_kernel<<<dim3(64, 2, 64), dim3(32, 8), 0, stream>>>(Vb, Vtb);
  pack_k_kernel<<<dim3(64 * 32), 256, 0, stream>>>(Kb, Kp);   // Kb -> Kp (@Vb)
  pack_v_kernel<<<dim3(64 * 32), 256, 0, stream>>>(Vtb, Vp);  // Vt -> Vp (@Kb)
  attn_kernel<<<dim3(1024), 256, 0, stream>>>(Qb, Kp, Vp, attb);
  ln_kernel<<<dim3(MTOT), 256, 0, stream>>>(attb, Rb, gamma, beta, out);
}

// Round 5
// 274.379 us; speedup vs baseline: 1.4927x; 1.1410x over previous
//
#include <hip/hip_runtime.h>

constexpr int B = 4, S = 2048, U = 1024, H = 16, DH = 64;
constexpr int MTOT = B * S;
constexpr int NT = S / 64;   // 32 key-tiles of 64

using bf16   = __bf16;
using f32x4  = __attribute__((ext_vector_type(4))) float;
using f32x16 = __attribute__((ext_vector_type(16))) float;
using bf16x8 = __attribute__((ext_vector_type(8))) bf16;
using bf16x4 = __attribute__((ext_vector_type(4))) bf16;
using u32x4  = __attribute__((ext_vector_type(4))) unsigned int;

__device__ __forceinline__ void gload16(const bf16* g, bf16* l) {
  __builtin_amdgcn_global_load_lds(
      (const __attribute__((address_space(1))) unsigned int*)g,
      (__attribute__((address_space(3))) unsigned int*)l, 16, 0, 0);
}

__device__ __forceinline__ float fexp2(float x) {
#if __has_builtin(__builtin_amdgcn_exp2f)
  return __builtin_amdgcn_exp2f(x);
#else
  return __expf(x * 0.6931471805599453f);
#endif
}

__device__ __forceinline__ f32x16 mfma32(bf16x8 a, bf16x8 b, f32x16 c) {
  return __builtin_amdgcn_mfma_f32_32x32x16_bf16(a, b, c, 0, 0, 0);
}

__device__ __forceinline__ unsigned packbf(float a, float b) {
  union { bf16 h; unsigned short s; } ua, ub;
  ua.h = (bf16)a; ub.h = (bf16)b;
  return ((unsigned)ub.s << 16) | (unsigned)ua.s;
}

// packed K layout: Kp[bh][t][tt][ks][ln][8] = K[s = t*64+tt*32+(ln&31)][h*64 + ks*16+(ln>>5)*8+j]
__device__ __forceinline__ size_t kpack_off(int M_, int col) {
  const int b = M_ >> 11, s = M_ & 2047;
  const int h = col >> 6, d = col & 63;
  const int bh = b * 16 + h;
  const int t = s >> 6, r64 = s & 63;
  const int tt = r64 >> 5, l31 = r64 & 31;
  const int ks = d >> 4, hi = (d >> 3) & 1, j = d & 7;
  const int ln = l31 + (hi << 5);
  return ((size_t)(bh * 32 + t) << 12) + (tt << 11) + (ks << 9) + (ln << 3) + j;
}

// packed V layout: Vp[bh][t][dt][ks][ln][8] = V[s = t*64+ks*16+(ln>>5)*8+j][h*64 + dt*32+(ln&31)]
__device__ __forceinline__ size_t vpack_off(int M_, int col) {
  const int b = M_ >> 11, s = M_ & 2047;
  const int h = col >> 6, d = col & 63;
  const int bh = b * 16 + h;
  const int j = s & 7, hi = (s >> 3) & 1, ks = (s >> 4) & 3, t = s >> 6;
  const int dt = d >> 5, l31 = d & 31;
  const int ln = l31 + (hi << 5);
  return ((size_t)(bh * 32 + t) << 12) + (dt << 11) + (ks << 9) + (ln << 3) + j;
}

// ---------- weight transpose + convert: Wt[n][k] = (bf16) W[k][n] ----------
__global__ void transpose_w_kernel(const float* __restrict__ w0, const float* __restrict__ w1,
                                   const float* __restrict__ w2, const float* __restrict__ w3,
                                   bf16* __restrict__ t0, bf16* __restrict__ t1,
                                   bf16* __restrict__ t2, bf16* __restrict__ t3) {
  const float* W = blockIdx.z == 0 ? w0 : blockIdx.z == 1 ? w1 : blockIdx.z == 2 ? w2 : w3;
  bf16* Wt       = blockIdx.z == 0 ? t0 : blockIdx.z == 1 ? t1 : blockIdx.z == 2 ? t2 : t3;
  __shared__ float tile[32][33];
  const int k0 = blockIdx.x * 32, n0 = blockIdx.y * 32;
  const int tx = threadIdx.x, ty = threadIdx.y;
  for (int i = ty; i < 32; i += 8) tile[i][tx] = W[(size_t)(k0 + i) * U + n0 + tx];
  __syncthreads();
  for (int i = ty; i < 32; i += 8) Wt[(size_t)(n0 + i) * U + k0 + tx] = (bf16)tile[tx][i];
}

// ---------- fp32 -> bf16 convert, all 3 inputs in one launch ----------
__global__ __launch_bounds__(256) void xcvt3_kernel(
    const float* __restrict__ x0, const float* __restrict__ x1, const float* __restrict__ x2,
    bf16* __restrict__ o0, bf16* __restrict__ o1, bf16* __restrict__ o2) {
  const float* x = blockIdx.z == 0 ? x0 : blockIdx.z == 1 ? x1 : x2;
  bf16* o       = blockIdx.z == 0 ? o0 : blockIdx.z == 1 ? o1 : o2;
  const size_t i = ((size_t)blockIdx.x * 256 + threadIdx.x) * 8;
  const float4 v0 = *reinterpret_cast<const float4*>(x + i);
  const float4 v1 = *reinterpret_cast<const float4*>(x + i + 4);
  bf16x8 r;
  r[0] = (bf16)v0.x; r[1] = (bf16)v0.y; r[2] = (bf16)v0.z; r[3] = (bf16)v0.w;
  r[4] = (bf16)v1.x; r[5] = (bf16)v1.y; r[6] = (bf16)v1.z; r[7] = (bf16)v1.w;
  *reinterpret_cast<bf16x8*>(o + i) = r;
}

// ---------- GEMM: out = relu(A @ Wt^T + b). MODE: 0=row-major, 1=K-pack, 2=V-pack ----------
template <int MODE>
__global__ __launch_bounds__(256) void gemm_kernel(
    const bf16* __restrict__ A, const bf16* __restrict__ Wt,
    const float* __restrict__ bias, bf16* __restrict__ out) {
  const int bn = blockIdx.x * 128, bm = blockIdx.y * 128;
  const int t = threadIdx.x, lane = t & 63, wid = t >> 6;
  const int wr = wid >> 1, wc = wid & 1;
  const int lm = lane & 15, hi = lane >> 4;

  __shared__ __align__(16) bf16 As[128][32];
  __shared__ __align__(16) bf16 Bs[128][32];

  f32x4 acc[4][4];
#pragma unroll
  for (int i = 0; i < 4; ++i)
#pragma unroll
    for (int j = 0; j < 4; ++j) acc[i][j] = f32x4{0.f, 0.f, 0.f, 0.f};

  const int srow = wid * 32 + (lane >> 2);
  const int scol = (lane & 3) * 8;
  const bf16* ga = A  + (size_t)(bm + srow) * U + scol;
  const bf16* gb = Wt + (size_t)(bn + srow) * U + scol;
  bf16* lA0 = &As[wid * 32][0];
  bf16* lA1 = &As[wid * 32 + 16][0];
  bf16* lB0 = &Bs[wid * 32][0];
  bf16* lB1 = &Bs[wid * 32 + 16][0];

  for (int k0 = 0; k0 < U; k0 += 32) {
    __syncthreads();
    gload16(ga + k0, lA0);
    gload16(ga + (size_t)16 * U + k0, lA1);
    gload16(gb + k0, lB0);
    gload16(gb + (size_t)16 * U + k0, lB1);
    __syncthreads();

    bf16x8 a[4], bb[4];
#pragma unroll
    for (int mi = 0; mi < 4; ++mi)
      a[mi] = *reinterpret_cast<const bf16x8*>(&As[wr * 64 + mi * 16 + lm][hi * 8]);
#pragma unroll
    for (int ni = 0; ni < 4; ++ni)
      bb[ni] = *reinterpret_cast<const bf16x8*>(&Bs[wc * 64 + ni * 16 + lm][hi * 8]);
#pragma unroll
    for (int mi = 0; mi < 4; ++mi)
#pragma unroll
      for (int ni = 0; ni < 4; ++ni)
        acc[mi][ni] = __builtin_amdgcn_mfma_f32_16x16x32_bf16(a[mi], bb[ni], acc[mi][ni], 0, 0, 0);
  }

  const int mb = bm + wr * 64 + hi * 4;
  const int nb = bn + wc * 64 + lm;
#pragma unroll
  for (int ni = 0; ni < 4; ++ni) {
    const float bv_ = bias[nb + ni * 16];
#pragma unroll
    for (int mi = 0; mi < 4; ++mi)
#pragma unroll
      for (int r = 0; r < 4; ++r) {
        float vv = acc[mi][ni][r] + bv_;
        vv = fmaxf(vv, 0.f);
        const int M_ = mb + mi * 16 + r;
        const int col = nb + ni * 16;
        if constexpr (MODE == 0) {
          out[(size_t)M_ * U + col] = (bf16)vv;
        } else if constexpr (MODE == 1) {
          out[kpack_off(M_, col)] = (bf16)vv;
        } else {
          out[vpack_off(M_, col)] = (bf16)vv;
        }
      }
  }
}

// ---------- flash attention: packed K/V, 3-buffer counted-vmcnt pipeline ----------
// 8 waves x 32 q-rows = 256 q-rows/block. Swapped QK^T (32x32x16), in-register softmax.
__global__ __launch_bounds__(512) void attn_kernel(
    const bf16* __restrict__ Q, const bf16* __restrict__ Kp,
    const bf16* __restrict__ Vp, bf16* __restrict__ att) {
  const int bid = blockIdx.x;
  const int swz = (bid & 7) * 64 + (bid >> 3);     // 8 bh per XCD, all q-blocks local
  const int bh = swz >> 3, qx = swz & 7;
  const int b = bh >> 4, h = bh & 15;
  const int tid = threadIdx.x;
  const int w = tid >> 6, lane = tid & 63;
  const int l31 = lane & 31, hi8 = lane >> 5;
  const int q0 = qx * 256 + w * 32;

  __shared__ __align__(16) bf16 kv[3][8192];   // [0..4095]=K tile, [4096..8191]=V tile

  const float qscale = 0.18033688011111606f;  // log2(e)/sqrt(DH)

  // Q fragments (B operand: col = q = l31, contraction = dh)
  const bf16* qbase = Q + ((size_t)b * S + q0 + l31) * U + h * DH + hi8 * 8;
  bf16x8 qf[4];
#pragma unroll
  for (int ks = 0; ks < 4; ++ks) {
    bf16x8 v = *reinterpret_cast<const bf16x8*>(qbase + ks * 16);
#pragma unroll
    for (int j = 0; j < 8; ++j) v[j] = (bf16)((float)v[j] * qscale);
    qf[ks] = v;
  }

  float m = -3e38f, lsum = 0.f;
  f32x16 o0 = (f32x16)0.f, o1 = (f32x16)0.f;

  const bf16* kpb = Kp + (size_t)bh * 32 * 4096;
  const bf16* vpb = Vp + (size_t)bh * 32 * 4096;

  // stage tiles 0,1 (2 gload16 per thread per tile)
  gload16(kpb + tid * 8, &kv[0][tid * 8]);
  gload16(vpb + tid * 8, &kv[0][4096 + tid * 8]);
  gload16(kpb + 4096 + tid * 8, &kv[1][tid * 8]);
  gload16(vpb + 4096 + tid * 8, &kv[1][4096 + tid * 8]);
  asm volatile("s_waitcnt vmcnt(2)" ::: "memory");   // tile 0 landed; tile 1 in flight
  __builtin_amdgcn_s_barrier();
  __builtin_amdgcn_sched_barrier(0);

  int cur = 0;
  for (int t = 0; t < NT; ++t) {
    // prefetch tile t+2 into buffer (cur+2)%3
    if (t + 2 < NT) {
      const int nb_ = cur + 2 >= 3 ? cur - 1 : cur + 2;
      gload16(kpb + (size_t)(t + 2) * 4096 + tid * 8, &kv[nb_][tid * 8]);
      gload16(vpb + (size_t)(t + 2) * 4096 + tid * 8, &kv[nb_][4096 + tid * 8]);
    }

    // K fragments (A operand: row = k) from LDS, contiguous per lane
    bf16x8 kf[2][4];
#pragma unroll
    for (int tt = 0; tt < 2; ++tt)
#pragma unroll
      for (int ks = 0; ks < 4; ++ks)
        kf[tt][ks] = *reinterpret_cast<const bf16x8*>(&kv[cur][(tt * 4 + ks) * 512 + lane * 8]);

    // S^T = K Q^T : rows = k (crow(r,hi8)), cols = q (l31)
    f32x16 s0 = (f32x16)0.f, s1 = (f32x16)0.f;
    __builtin_amdgcn_s_setprio(1);
#pragma unroll
    for (int ks = 0; ks < 4; ++ks) {
      s0 = mfma32(kf[0][ks], qf[ks], s0);
      s1 = mfma32(kf[1][ks], qf[ks], s1);
    }
    __builtin_amdgcn_s_setprio(0);

    // V fragments (B operand for PV); LDS reads issued early, overlap softmax
    bf16x8 vf[2][4];
#pragma unroll
    for (int dt = 0; dt < 2; ++dt)
#pragma unroll
      for (int ks = 0; ks < 4; ++ks)
        vf[dt][ks] = *reinterpret_cast<const bf16x8*>(&kv[cur][4096 + (dt * 4 + ks) * 512 + lane * 8]);

    // in-lane max over own 32 keys (tree), merge with partner lane^32
    float mx8[8];
#pragma unroll
    for (int i = 0; i < 8; ++i)
      mx8[i] = fmaxf(fmaxf(s0[i], s0[i + 8]), fmaxf(s1[i], s1[i + 8]));
    float mx = fmaxf(fmaxf(fmaxf(mx8[0], mx8[1]), fmaxf(mx8[2], mx8[3])),
                     fmaxf(fmaxf(mx8[4], mx8[5]), fmaxf(mx8[6], mx8[7])));
    mx = fmaxf(mx, __shfl_xor(mx, 32));

    // defer-max: rescale only when max grew > 8 (log2 domain)
    if (__any(mx > m + 8.f)) {
      const float mn = fmaxf(m, mx);
      const float f = fexp2(m - mn);
      m = mn;
      lsum *= f;
#pragma unroll
      for (int r = 0; r < 16; ++r) {
        const float fr = __shfl(f, (r & 3) + 8 * (r >> 2) + 4 * hi8);
        o0[r] *= fr;
        o1[r] *= fr;
      }
    }

    // P = exp2(S - m): lane-local; pack to bf16 pairs
    unsigned wpk[16], owpk[16];
    float ps0 = 0.f, ps1 = 0.f, ps2 = 0.f, ps3 = 0.f;
#pragma unroll
    for (int i = 0; i < 8; ++i) {
      const float pa = fexp2(s0[2 * i] - m);
      const float pb = fexp2(s0[2 * i + 1] - m);
      ps0 += pa; ps1 += pb;
      wpk[i] = packbf(pa, pb);
      const float pc = fexp2(s1[2 * i] - m);
      const float pd = fexp2(s1[2 * i + 1] - m);
      ps2 += pc; ps3 += pd;
      wpk[8 + i] = packbf(pc, pd);
    }
    float ps = (ps0 + ps1) + (ps2 + ps3);
    ps += __shfl_xor(ps, 32);
    lsum += ps;

    // exchange halves with partner lane
#pragma unroll
    for (int i = 0; i < 16; ++i) owpk[i] = __shfl_xor(wpk[i], 32);

    // assemble A-fragments of P: fw[ks] covers k = ks*16 + hi8*8 + j
    u32x4 fw[4];
    fw[0] = hi8 ? u32x4{owpk[2], owpk[3], wpk[2], wpk[3]}
                : u32x4{wpk[0], wpk[1], owpk[0], owpk[1]};
    fw[1] = hi8 ? u32x4{owpk[6], owpk[7], wpk[6], wpk[7]}
                : u32x4{wpk[4], wpk[5], owpk[4], owpk[5]};
    fw[2] = hi8 ? u32x4{owpk[10], owpk[11], wpk[10], wpk[11]}
                : u32x4{wpk[8], wpk[9], owpk[8], owpk[9]};
    fw[3] = hi8 ? u32x4{owpk[14], owpk[15], wpk[14], wpk[15]}
                : u32x4{wpk[12], wpk[13], owpk[12], owpk[13]};

    // O += P V : rows = q (crow), cols = d (dtile*32 + l31)
    __builtin_amdgcn_s_setprio(1);
#pragma unroll
    for (int ks = 0; ks < 4; ++ks) {
      const bf16x8 pf = __builtin_bit_cast(bf16x8, fw[ks]);
      o0 = mfma32(pf, vf[0][ks], o0);
      o1 = mfma32(pf, vf[1][ks], o1);
    }
    __builtin_amdgcn_s_setprio(0);

    // counted wait: tile t+1 landed, tile t+2 stays in flight across the barrier
    if (t + 1 < NT) {
      if (t + 2 < NT) asm volatile("s_waitcnt vmcnt(2)" ::: "memory");
      else            asm volatile("s_waitcnt vmcnt(0)" ::: "memory");
      __builtin_amdgcn_s_barrier();
      __builtin_amdgcn_sched_barrier(0);
    }
    cur = cur + 1 >= 3 ? 0 : cur + 1;
  }

  // normalize (1/lsum lives at lane q) + store
  const float linv = 1.f / lsum;
  bf16* obase = att + ((size_t)b * S + q0) * U + h * DH + l31;
#pragma unroll
  for (int r = 0; r < 16; ++r) {
    const int row = (r & 3) + 8 * (r >> 2) + 4 * hi8;
    const float lr = __shfl(linv, row);
    obase[(size_t)row * U]      = (bf16)(o0[r] * lr);
    obase[(size_t)row * U + 32] = (bf16)(o1[r] * lr);
  }
}

// ---------- epilogue: x = relu(att + vres); LayerNorm(x)*gamma + beta ----------
__global__ __launch_bounds__(256) void ln_kernel(
    const bf16* __restrict__ att, const bf16* __restrict__ vres,
    const float* __restrict__ gamma, const float* __restrict__ beta,
    float* __restrict__ out) {
  const int row = blockIdx.x;
  const int t = threadIdx.x;
  const bf16* ar = att + (size_t)row * U;
  const bf16* vr = vres + (size_t)row * U;
  const bf16x4 av = *reinterpret_cast<const bf16x4*>(ar + t * 4);
  const bf16x4 vv = *reinterpret_cast<const bf16x4*>(vr + t * 4);
  float x[4];
  float sum = 0.f, sq = 0.f;
#pragma unroll
  for (int i = 0; i < 4; ++i) {
    x[i] = fmaxf((float)av[i] + (float)vv[i], 0.f);
    sum += x[i];
    sq += x[i] * x[i];
  }
#pragma unroll
  for (int mm = 1; mm < 64; mm <<= 1) {
    sum += __shfl_xor(sum, mm);
    sq  += __shfl_xor(sq, mm);
  }
  __shared__ float s1[4], s2[4];
  if ((t & 63) == 0) { s1[t >> 6] = sum; s2[t >> 6] = sq; }
  __syncthreads();
  sum = s1[0] + s1[1] + s1[2] + s1[3];
  sq  = s2[0] + s2[1] + s2[2] + s2[3];
  const float mean = sum * (1.f / U);
  float var = sq * (1.f / U) - mean * mean;
  var = fmaxf(var, 0.f);
  const float inv = rsqrtf(var + 1e-8f);
#pragma unroll
  for (int i = 0; i < 4; ++i) {
    const int c = t * 4 + i;
    out[(size_t)row * U + c] = gamma[c] * ((x[i] - mean) * inv) + beta[c];
  }
}

extern "C" void kernel_launch(void* const* d_in, const int* in_sizes, int n_in,
                              void* d_out, int out_size, void* d_ws, size_t ws_size,
                              hipStream_t stream) {
  const float* queries = (const float*)d_in[0];
  const float* keys    = (const float*)d_in[1];
  const float* values  = (const float*)d_in[2];
  const float* Wq = (const float*)d_in[3];
  const float* bq = (const float*)d_in[4];
  const float* Wk = (const float*)d_in[5];
  const float* bk = (const float*)d_in[6];
  const float* Wv = (const float*)d_in[7];
  const float* bv = (const float*)d_in[8];
  const float* Wr = (const float*)d_in[9];
  const float* br = (const float*)d_in[10];
  const float* gamma = (const float*)d_in[11];
  const float* beta  = (const float*)d_in[12];
  float* out = (float*)d_out;

  char* ws = (char*)d_ws;
  const size_t MB = 1024 * 1024;
  bf16* wqt  = (bf16*)(ws + 0 * MB);
  bf16* wkt  = (bf16*)(ws + 2 * MB);
  bf16* wvt  = (bf16*)(ws + 4 * MB);
  bf16* wrt  = (bf16*)(ws + 6 * MB);
  bf16* Qcvt = (bf16*)(ws + 8 * MB);    // dead after Q-gemm -> attb aliases
  bf16* Kcvt = (bf16*)(ws + 24 * MB);   // dead after K-gemm -> Rb aliases
  bf16* Vcvt = (bf16*)(ws + 40 * MB);
  bf16* Qb   = (bf16*)(ws + 56 * MB);
  bf16* Kp   = (bf16*)(ws + 72 * MB);
  bf16* Vp   = (bf16*)(ws + 88 * MB);   // total 104 MB
  bf16* attb = Qcvt;
  bf16* Rb   = Kcvt;

  transpose_w_kernel<<<dim3(32, 32, 4), dim3(32, 8), 0, stream>>>(
      Wq, Wk, Wv, Wr, wqt, wkt, wvt, wrt);
  xcvt3_kernel<<<dim3(4096, 1, 3), 256, 0, stream>>>(queries, keys, values, Qcvt, Kcvt, Vcvt);
  gemm_kernel<0><<<dim3(8, 64), 256, 0, stream>>>(Qcvt, wqt, bq, Qb);
  gemm_kernel<1><<<dim3(8, 64), 256, 0, stream>>>(Kcvt, wkt, bk, Kp);
  gemm_kernel<2><<<dim3(8, 64), 256, 0, stream>>>(Vcvt, wvt, bv, Vp);
  gemm_kernel<0><<<dim3(8, 64), 256, 0, stream>>>(Vcvt, wrt, br, Rb);
  attn_kernel<<<dim3(512), 512, 0, stream>>>(Qb, Kp, Vp, attb);
  ln_kernel<<<dim3(MTOT), 256, 0, stream>>>(attb, Rb, gamma, beta, out);
}

// Round 6
// 267.818 us; speedup vs baseline: 1.5293x; 1.0245x over previous
//
#include <hip/hip_runtime.h>

constexpr int B = 4, S = 2048, U = 1024, H = 16, DH = 64;
constexpr int MTOT = B * S;
constexpr int NT = S / 64;   // 32 key-tiles of 64

using bf16   = __bf16;
using f32x4  = __attribute__((ext_vector_type(4))) float;
using f32x16 = __attribute__((ext_vector_type(16))) float;
using bf16x8 = __attribute__((ext_vector_type(8))) bf16;
using bf16x4 = __attribute__((ext_vector_type(4))) bf16;
using u32x4  = __attribute__((ext_vector_type(4))) unsigned int;

__device__ __forceinline__ void gload16(const bf16* g, bf16* l) {
  __builtin_amdgcn_global_load_lds(
      (const __attribute__((address_space(1))) unsigned int*)g,
      (__attribute__((address_space(3))) unsigned int*)l, 16, 0, 0);
}

__device__ __forceinline__ float fexp2(float x) {
#if __has_builtin(__builtin_amdgcn_exp2f)
  return __builtin_amdgcn_exp2f(x);
#else
  return __expf(x * 0.6931471805599453f);
#endif
}

__device__ __forceinline__ f32x16 mfma32(bf16x8 a, bf16x8 b, f32x16 c) {
  return __builtin_amdgcn_mfma_f32_32x32x16_bf16(a, b, c, 0, 0, 0);
}

__device__ __forceinline__ unsigned packbf(float a, float b) {
  union { bf16 h; unsigned short s; } ua, ub;
  ua.h = (bf16)a; ub.h = (bf16)b;
  return ((unsigned)ub.s << 16) | (unsigned)ua.s;
}

// packed K layout: Kp[bh][t][tt][ks][ln][8] = K[s = t*64+tt*32+(ln&31)][h*64 + ks*16+(ln>>5)*8+j]
__device__ __forceinline__ size_t kpack_off(int M_, int col) {
  const int b = M_ >> 11, s = M_ & 2047;
  const int h = col >> 6, d = col & 63;
  const int bh = b * 16 + h;
  const int t = s >> 6, r64 = s & 63;
  const int tt = r64 >> 5, l31 = r64 & 31;
  const int ks = d >> 4, hi = (d >> 3) & 1, j = d & 7;
  const int ln = l31 + (hi << 5);
  return ((size_t)(bh * 32 + t) << 12) + (tt << 11) + (ks << 9) + (ln << 3) + j;
}

// packed V layout: Vp[bh][t][dt][ks][ln][8] = V[s = t*64+ks*16+(ln>>5)*8+j][h*64 + dt*32+(ln&31)]
__device__ __forceinline__ size_t vpack_off(int M_, int col) {
  const int b = M_ >> 11, s = M_ & 2047;
  const int h = col >> 6, d = col & 63;
  const int bh = b * 16 + h;
  const int j = s & 7, hi = (s >> 3) & 1, ks = (s >> 4) & 3, t = s >> 6;
  const int dt = d >> 5, l31 = d & 31;
  const int ln = l31 + (hi << 5);
  return ((size_t)(bh * 32 + t) << 12) + (dt << 11) + (ks << 9) + (ln << 3) + j;
}

// ---------- weight transpose + convert: Wt[n][k] = (bf16) W[k][n] ----------
__global__ void transpose_w_kernel(const float* __restrict__ w0, const float* __restrict__ w1,
                                   const float* __restrict__ w2, const float* __restrict__ w3,
                                   bf16* __restrict__ t0, bf16* __restrict__ t1,
                                   bf16* __restrict__ t2, bf16* __restrict__ t3) {
  const float* W = blockIdx.z == 0 ? w0 : blockIdx.z == 1 ? w1 : blockIdx.z == 2 ? w2 : w3;
  bf16* Wt       = blockIdx.z == 0 ? t0 : blockIdx.z == 1 ? t1 : blockIdx.z == 2 ? t2 : t3;
  __shared__ float tile[32][33];
  const int k0 = blockIdx.x * 32, n0 = blockIdx.y * 32;
  const int tx = threadIdx.x, ty = threadIdx.y;
  for (int i = ty; i < 32; i += 8) tile[i][tx] = W[(size_t)(k0 + i) * U + n0 + tx];
  __syncthreads();
  for (int i = ty; i < 32; i += 8) Wt[(size_t)(n0 + i) * U + k0 + tx] = (bf16)tile[tx][i];
}

// ---------- fp32 -> bf16 convert, all 3 inputs in one launch ----------
__global__ __launch_bounds__(256) void xcvt3_kernel(
    const float* __restrict__ x0, const float* __restrict__ x1, const float* __restrict__ x2,
    bf16* __restrict__ o0, bf16* __restrict__ o1, bf16* __restrict__ o2) {
  const float* x = blockIdx.z == 0 ? x0 : blockIdx.z == 1 ? x1 : x2;
  bf16* o       = blockIdx.z == 0 ? o0 : blockIdx.z == 1 ? o1 : o2;
  const size_t i = ((size_t)blockIdx.x * 256 + threadIdx.x) * 8;
  const float4 v0 = *reinterpret_cast<const float4*>(x + i);
  const float4 v1 = *reinterpret_cast<const float4*>(x + i + 4);
  bf16x8 r;
  r[0] = (bf16)v0.x; r[1] = (bf16)v0.y; r[2] = (bf16)v0.z; r[3] = (bf16)v0.w;
  r[4] = (bf16)v1.x; r[5] = (bf16)v1.y; r[6] = (bf16)v1.z; r[7] = (bf16)v1.w;
  *reinterpret_cast<bf16x8*>(o + i) = r;
}

// ---------- GEMM: out = relu(A @ Wt^T + b). MODE: 0=row-major, 1=K-pack, 2=V-pack ----------
template <int MODE>
__global__ __launch_bounds__(256) void gemm_kernel(
    const bf16* __restrict__ A, const bf16* __restrict__ Wt,
    const float* __restrict__ bias, bf16* __restrict__ out) {
  const int bn = blockIdx.x * 128, bm = blockIdx.y * 128;
  const int t = threadIdx.x, lane = t & 63, wid = t >> 6;
  const int wr = wid >> 1, wc = wid & 1;
  const int lm = lane & 15, hi = lane >> 4;

  __shared__ __align__(16) bf16 As[128][32];
  __shared__ __align__(16) bf16 Bs[128][32];

  f32x4 acc[4][4];
#pragma unroll
  for (int i = 0; i < 4; ++i)
#pragma unroll
    for (int j = 0; j < 4; ++j) acc[i][j] = f32x4{0.f, 0.f, 0.f, 0.f};

  const int srow = wid * 32 + (lane >> 2);
  const int scol = (lane & 3) * 8;
  const bf16* ga = A  + (size_t)(bm + srow) * U + scol;
  const bf16* gb = Wt + (size_t)(bn + srow) * U + scol;
  bf16* lA0 = &As[wid * 32][0];
  bf16* lA1 = &As[wid * 32 + 16][0];
  bf16* lB0 = &Bs[wid * 32][0];
  bf16* lB1 = &Bs[wid * 32 + 16][0];

  for (int k0 = 0; k0 < U; k0 += 32) {
    __syncthreads();
    gload16(ga + k0, lA0);
    gload16(ga + (size_t)16 * U + k0, lA1);
    gload16(gb + k0, lB0);
    gload16(gb + (size_t)16 * U + k0, lB1);
    __syncthreads();

    bf16x8 a[4], bb[4];
#pragma unroll
    for (int mi = 0; mi < 4; ++mi)
      a[mi] = *reinterpret_cast<const bf16x8*>(&As[wr * 64 + mi * 16 + lm][hi * 8]);
#pragma unroll
    for (int ni = 0; ni < 4; ++ni)
      bb[ni] = *reinterpret_cast<const bf16x8*>(&Bs[wc * 64 + ni * 16 + lm][hi * 8]);
#pragma unroll
    for (int mi = 0; mi < 4; ++mi)
#pragma unroll
      for (int ni = 0; ni < 4; ++ni)
        acc[mi][ni] = __builtin_amdgcn_mfma_f32_16x16x32_bf16(a[mi], bb[ni], acc[mi][ni], 0, 0, 0);
  }

  const int mb = bm + wr * 64 + hi * 4;
  const int nb = bn + wc * 64 + lm;
#pragma unroll
  for (int ni = 0; ni < 4; ++ni) {
    const float bv_ = bias[nb + ni * 16];
#pragma unroll
    for (int mi = 0; mi < 4; ++mi)
#pragma unroll
      for (int r = 0; r < 4; ++r) {
        float vv = acc[mi][ni][r] + bv_;
        vv = fmaxf(vv, 0.f);
        const int M_ = mb + mi * 16 + r;
        const int col = nb + ni * 16;
        if constexpr (MODE == 0) {
          out[(size_t)M_ * U + col] = (bf16)vv;
        } else if constexpr (MODE == 1) {
          out[kpack_off(M_, col)] = (bf16)vv;
        } else {
          out[vpack_off(M_, col)] = (bf16)vv;
        }
      }
  }
}

// ---------- flash attention: packed K/V, 3-buffer counted-vmcnt pipeline ----------
// 8 waves x 32 q-rows. Swapped QK^T (32x32x16); softmax fully in-register:
// row-sum via ones-MFMA, half-exchange via v_permlane32_swap_b32, C_init = -m.
__global__ __launch_bounds__(512, 4) void attn_kernel(
    const bf16* __restrict__ Q, const bf16* __restrict__ Kp,
    const bf16* __restrict__ Vp, bf16* __restrict__ att) {
  const int bid = blockIdx.x;
  const int swz = (bid & 7) * 64 + (bid >> 3);     // 8 bh per XCD
  const int bh = swz >> 3, qx = swz & 7;
  const int b = bh >> 4, h = bh & 15;
  const int tid = threadIdx.x;
  const int w = tid >> 6, lane = tid & 63;
  const int l31 = lane & 31, hi8 = lane >> 5;
  const int q0 = qx * 256 + w * 32;

  __shared__ __align__(16) bf16 kv[3][8192];   // [0..4095]=K tile, [4096..8191]=V tile

  const float qscale = 0.18033688011111606f;  // log2(e)/sqrt(DH)

  // Q fragments (B operand: col = q = l31, contraction = dh)
  const bf16* qbase = Q + ((size_t)b * S + q0 + l31) * U + h * DH + hi8 * 8;
  bf16x8 qf[4];
#pragma unroll
  for (int ks = 0; ks < 4; ++ks) {
    bf16x8 v = *reinterpret_cast<const bf16x8*>(qbase + ks * 16);
#pragma unroll
    for (int j = 0; j < 8; ++j) v[j] = (bf16)((float)v[j] * qscale);
    qf[ks] = v;
  }

  bf16x8 onesf;
#pragma unroll
  for (int j = 0; j < 8; ++j) onesf[j] = (bf16)1.f;

  // m = running max (log2 domain). Scores >= 0 here (post-ReLU Q,K), so m=0 is valid.
  float m = 0.f;
  f32x16 o0 = (f32x16)0.f, o1 = (f32x16)0.f, osum = (f32x16)0.f;

  const bf16* kpb = Kp + (size_t)bh * 32 * 4096;
  const bf16* vpb = Vp + (size_t)bh * 32 * 4096;

  gload16(kpb + tid * 8, &kv[0][tid * 8]);
  gload16(vpb + tid * 8, &kv[0][4096 + tid * 8]);
  gload16(kpb + 4096 + tid * 8, &kv[1][tid * 8]);
  gload16(vpb + 4096 + tid * 8, &kv[1][4096 + tid * 8]);
  asm volatile("s_waitcnt vmcnt(2)" ::: "memory");
  __builtin_amdgcn_s_barrier();
  __builtin_amdgcn_sched_barrier(0);

  int cur = 0;
  for (int t = 0; t < NT; ++t) {
    if (t + 2 < NT) {
      const int nb_ = cur + 2 >= 3 ? cur - 1 : cur + 2;
      gload16(kpb + (size_t)(t + 2) * 4096 + tid * 8, &kv[nb_][tid * 8]);
      gload16(vpb + (size_t)(t + 2) * 4096 + tid * 8, &kv[nb_][4096 + tid * 8]);
    }

    bf16x8 kf[2][4];
#pragma unroll
    for (int tt = 0; tt < 2; ++tt)
#pragma unroll
      for (int ks = 0; ks < 4; ++ks)
        kf[tt][ks] = *reinterpret_cast<const bf16x8*>(&kv[cur][(tt * 4 + ks) * 512 + lane * 8]);

    // S^T = K Q^T with C initialized to -m  ->  s holds (score - m) directly
    f32x16 s0 = (f32x16)(-m), s1 = (f32x16)(-m);
    __builtin_amdgcn_s_setprio(1);
#pragma unroll
    for (int ks = 0; ks < 4; ++ks) {
      s0 = mfma32(kf[0][ks], qf[ks], s0);
      s1 = mfma32(kf[1][ks], qf[ks], s1);
    }
    __builtin_amdgcn_s_setprio(0);

    bf16x8 vf[2][4];
#pragma unroll
    for (int dt = 0; dt < 2; ++dt)
#pragma unroll
      for (int ks = 0; ks < 4; ++ks)
        vf[dt][ks] = *reinterpret_cast<const bf16x8*>(&kv[cur][4096 + (dt * 4 + ks) * 512 + lane * 8]);

    // tile max (relative to m): in-lane tree + cross-half permlane swap
    float mx8[8];
#pragma unroll
    for (int i = 0; i < 8; ++i)
      mx8[i] = fmaxf(fmaxf(s0[i], s0[i + 8]), fmaxf(s1[i], s1[i + 8]));
    float mx = fmaxf(fmaxf(fmaxf(mx8[0], mx8[1]), fmaxf(mx8[2], mx8[3])),
                     fmaxf(fmaxf(mx8[4], mx8[5]), fmaxf(mx8[6], mx8[7])));
    {
      float ma = mx, mb_ = mx;
      asm("v_permlane32_swap_b32 %0, %1" : "+v"(ma), "+v"(mb_));
      mx = fmaxf(ma, mb_);
    }

    // defer-max: only rescale when relative max grew past 8
    if (__any(mx > 8.f)) {
      const float d = fmaxf(mx, 0.f);
      const float f = fexp2(-d);
      m += d;
#pragma unroll
      for (int i = 0; i < 16; ++i) { s0[i] -= d; s1[i] -= d; }
#pragma unroll
      for (int r = 0; r < 16; ++r) {
        const float fr = __shfl(f, (r & 3) + 8 * (r >> 2) + 4 * hi8);
        o0[r] *= fr;
        o1[r] *= fr;
        osum[r] *= fr;
      }
    }

    // P = exp2(s) lane-local; pack to bf16 pairs
    unsigned wpk[16];
#pragma unroll
    for (int i = 0; i < 8; ++i) {
      wpk[i]     = packbf(fexp2(s0[2 * i]), fexp2(s0[2 * i + 1]));
      wpk[8 + i] = packbf(fexp2(s1[2 * i]), fexp2(s1[2 * i + 1]));
    }

    // half-exchange via permlane32_swap: A'={A.lo,B.lo-from-partner}, B'={A.hi-from-partner,B.hi}
    u32x4 fw[4];
#pragma unroll
    for (int fi = 0; fi < 4; ++fi) {
      unsigned a0 = wpk[fi * 4 + 0], b0 = wpk[fi * 4 + 2];
      unsigned a1 = wpk[fi * 4 + 1], b1 = wpk[fi * 4 + 3];
      asm("v_permlane32_swap_b32 %0, %1" : "+v"(a0), "+v"(b0));
      asm("v_permlane32_swap_b32 %0, %1" : "+v"(a1), "+v"(b1));
      fw[fi] = u32x4{a0, a1, b0, b1};
    }

    // O += P V ; row-sum += P * ones  (denominator in the matrix pipe, same C layout)
    __builtin_amdgcn_s_setprio(1);
#pragma unroll
    for (int ks = 0; ks < 4; ++ks) {
      const bf16x8 pf = __builtin_bit_cast(bf16x8, fw[ks]);
      o0   = mfma32(pf, vf[0][ks], o0);
      o1   = mfma32(pf, vf[1][ks], o1);
      osum = mfma32(pf, onesf, osum);
    }
    __builtin_amdgcn_s_setprio(0);

    if (t + 1 < NT) {
      if (t + 2 < NT) asm volatile("s_waitcnt vmcnt(2)" ::: "memory");
      else            asm volatile("s_waitcnt vmcnt(0)" ::: "memory");
      __builtin_amdgcn_s_barrier();
      __builtin_amdgcn_sched_barrier(0);
    }
    cur = cur + 1 >= 3 ? 0 : cur + 1;
  }

  // normalize + store: osum[r] matches o0[r]/o1[r] row-for-row -> no shuffles
  bf16* obase = att + ((size_t)b * S + q0) * U + h * DH + l31;
#pragma unroll
  for (int r = 0; r < 16; ++r) {
    const int row = (r & 3) + 8 * (r >> 2) + 4 * hi8;
    const float lr = 1.f / osum[r];
    obase[(size_t)row * U]      = (bf16)(o0[r] * lr);
    obase[(size_t)row * U + 32] = (bf16)(o1[r] * lr);
  }
}

// ---------- epilogue: x = relu(att + vres); LayerNorm(x)*gamma + beta ----------
__global__ __launch_bounds__(256) void ln_kernel(
    const bf16* __restrict__ att, const bf16* __restrict__ vres,
    const float* __restrict__ gamma, const float* __restrict__ beta,
    float* __restrict__ out) {
  const int row = blockIdx.x;
  const int t = threadIdx.x;
  const bf16* ar = att + (size_t)row * U;
  const bf16* vr = vres + (size_t)row * U;
  const bf16x4 av = *reinterpret_cast<const bf16x4*>(ar + t * 4);
  const bf16x4 vv = *reinterpret_cast<const bf16x4*>(vr + t * 4);
  float x[4];
  float sum = 0.f, sq = 0.f;
#pragma unroll
  for (int i = 0; i < 4; ++i) {
    x[i] = fmaxf((float)av[i] + (float)vv[i], 0.f);
    sum += x[i];
    sq += x[i] * x[i];
  }
#pragma unroll
  for (int mm = 1; mm < 64; mm <<= 1) {
    sum += __shfl_xor(sum, mm);
    sq  += __shfl_xor(sq, mm);
  }
  __shared__ float s1[4], s2[4];
  if ((t & 63) == 0) { s1[t >> 6] = sum; s2[t >> 6] = sq; }
  __syncthreads();
  sum = s1[0] + s1[1] + s1[2] + s1[3];
  sq  = s2[0] + s2[1] + s2[2] + s2[3];
  const float mean = sum * (1.f / U);
  float var = sq * (1.f / U) - mean * mean;
  var = fmaxf(var, 0.f);
  const float inv = rsqrtf(var + 1e-8f);
#pragma unroll
  for (int i = 0; i < 4; ++i) {
    const int c = t * 4 + i;
    out[(size_t)row * U + c] = gamma[c] * ((x[i] - mean) * inv) + beta[c];
  }
}

extern "C" void kernel_launch(void* const* d_in, const int* in_sizes, int n_in,
                              void* d_out, int out_size, void* d_ws, size_t ws_size,
                              hipStream_t stream) {
  const float* queries = (const float*)d_in[0];
  const float* keys    = (const float*)d_in[1];
  const float* values  = (const float*)d_in[2];
  const float* Wq = (const float*)d_in[3];
  const float* bq = (const float*)d_in[4];
  const float* Wk = (const float*)d_in[5];
  const float* bk = (const float*)d_in[6];
  const float* Wv = (const float*)d_in[7];
  const float* bv = (const float*)d_in[8];
  const float* Wr = (const float*)d_in[9];
  const float* br = (const float*)d_in[10];
  const float* gamma = (const float*)d_in[11];
  const float* beta  = (const float*)d_in[12];
  float* out = (float*)d_out;

  char* ws = (char*)d_ws;
  const size_t MB = 1024 * 1024;
  bf16* wqt  = (bf16*)(ws + 0 * MB);
  bf16* wkt  = (bf16*)(ws + 2 * MB);
  bf16* wvt  = (bf16*)(ws + 4 * MB);
  bf16* wrt  = (bf16*)(ws + 6 * MB);
  bf16* Qcvt = (bf16*)(ws + 8 * MB);    // dead after Q-gemm -> attb aliases
  bf16* Kcvt = (bf16*)(ws + 24 * MB);   // dead after K-gemm -> Rb aliases
  bf16* Vcvt = (bf16*)(ws + 40 * MB);
  bf16* Qb   = (bf16*)(ws + 56 * MB);
  bf16* Kp   = (bf16*)(ws + 72 * MB);
  bf16* Vp   = (bf16*)(ws + 88 * MB);   // total 104 MB
  bf16* attb = Qcvt;
  bf16* Rb   = Kcvt;

  transpose_w_kernel<<<dim3(32, 32, 4), dim3(32, 8), 0, stream>>>(
      Wq, Wk, Wv, Wr, wqt, wkt, wvt, wrt);
  xcvt3_kernel<<<dim3(4096, 1, 3), 256, 0, stream>>>(queries, keys, values, Qcvt, Kcvt, Vcvt);
  gemm_kernel<0><<<dim3(8, 64), 256, 0, stream>>>(Qcvt, wqt, bq, Qb);
  gemm_kernel<1><<<dim3(8, 64), 256, 0, stream>>>(Kcvt, wkt, bk, Kp);
  gemm_kernel<2><<<dim3(8, 64), 256, 0, stream>>>(Vcvt, wvt, bv, Vp);
  gemm_kernel<0><<<dim3(8, 64), 256, 0, stream>>>(Vcvt, wrt, br, Rb);
  attn_kernel<<<dim3(512), 512, 0, stream>>>(Qb, Kp, Vp, attb);
  ln_kernel<<<dim3(MTOT), 256, 0, stream>>>(attb, Rb, gamma, beta, out);
}